// Round 14
// baseline (860.689 us; speedup 1.0000x reference)
//
#include <hip/hip_runtime.h>
#include <math.h>

static constexpr int H = 256, W = 256, HW = H * W;

typedef __attribute__((ext_vector_type(8))) _Float16 half8v;  // 16B
typedef __attribute__((ext_vector_type(4))) _Float16 half4v;  // 8B
typedef __attribute__((ext_vector_type(4))) float  float4v;   // MFMA acc

__device__ __forceinline__ half8v h8zero() {
  half8v z;
  #pragma unroll
  for (int i = 0; i < 8; ++i) z[i] = (_Float16)0;
  return z;
}

// ---------- activations ----------
__device__ __forceinline__ float gelu_f(float v) {
  return 0.5f * v * (1.0f + erff(v * 0.70710678118654752440f));
}
template<int ACT>
__device__ __forceinline__ float apply_act(float v) {
  if constexpr (ACT == 1) return v >= 0.f ? v : 0.1f * v;   // LeakyReLU(0.1)
  if constexpr (ACT == 2) return gelu_f(v);
  return v;
}

// ---------- pack both inputs: NCHW f32 (C=32) -> chunked NHWC f16 hi + scaled lo ----------
__global__ __launch_bounds__(256)
void pack2_k(const float* __restrict__ inA, _Float16* __restrict__ hiA, _Float16* __restrict__ loA,
             const float* __restrict__ inB, _Float16* __restrict__ hiB, _Float16* __restrict__ loB)
{
  const int p = blockIdx.x * 256 + threadIdx.x;
  const int b = blockIdx.y;
  const float* in = blockIdx.z ? inB : inA;
  _Float16* hi = blockIdx.z ? hiB : hiA;
  _Float16* lo = blockIdx.z ? loB : loA;
  const float* ip = in + (size_t)b * 32 * HW + p;
  __attribute__((aligned(16))) _Float16 hv[32], lv[32];
  #pragma unroll
  for (int c = 0; c < 32; ++c) {
    float v = ip[(size_t)c * HW];
    _Float16 h = (_Float16)v;
    hv[c] = h;
    lv[c] = (_Float16)((v - (float)h) * 2048.0f);
  }
  size_t ob = ((size_t)b * HW + p) * 32;
  #pragma unroll
  for (int j = 0; j < 4; ++j) {
    *(half8v*)&hi[ob + j * 8] = *(half8v*)&hv[j * 8];
    *(half8v*)&lo[ob + j * 8] = *(half8v*)&lv[j * 8];
  }
}

// ---------- weight prep x3: [OC][CIN][3][3] f32 -> [tap][OC][CIN] f16 hi + scaled lo ----------
__device__ __forceinline__ void prep_w_body(const float* w, _Float16* hi, _Float16* lo,
                                            int OC, int CIN, int tid)
{
  if (tid >= OC * CIN * 9) return;
  int ci = tid % CIN; int r = tid / CIN; int oc = r % OC; int tap = r / OC;
  float v = w[((size_t)oc * CIN + ci) * 9 + tap];
  _Float16 h = (_Float16)v;
  hi[tid] = h;
  lo[tid] = (_Float16)((v - (float)h) * 2048.0f);
}
__global__ __launch_bounds__(256)
void prep3_w_k(const float* __restrict__ w0, _Float16* __restrict__ h0, _Float16* __restrict__ l0, int OC0, int CIN0, int nb0,
               const float* __restrict__ w1, _Float16* __restrict__ h1, _Float16* __restrict__ l1, int OC1, int CIN1, int nb1,
               const float* __restrict__ w2, _Float16* __restrict__ h2, _Float16* __restrict__ l2, int OC2, int CIN2)
{
  int bb = blockIdx.x;
  if (bb < nb0)            prep_w_body(w0, h0, l0, OC0, CIN0, bb * 256 + threadIdx.x);
  else if (bb < nb0 + nb1) prep_w_body(w1, h1, l1, OC1, CIN1, (bb - nb0) * 256 + threadIdx.x);
  else                     prep_w_body(w2, h2, l2, OC2, CIN2, (bb - nb0 - nb1) * 256 + threadIdx.x);
}

// ---------- 3x3 conv, f16 MFMA; F=2 narrow tile for the VGPR<=~80 bracket ----------
// r8/r11 data: VGPR<=76 -> ~32% occupancy; >=88 -> 22% plateau. acc is the big
// consumer, so the wave tile is 32 px (F=2): acc = 32 regs (split-3 OCB=32).
// Full LDS staging of hi+lo ([6][34][64] halves = 26.1 KB, r10-verified layout
// scaled to 34 px) -> no per-tap global B loads (r11's L1 wall), no manual
// pipelining (r13 regression). Weights per tap from global (L2-hot).
// SPLIT=3: split-3 (accP + accQ/2048) — pre-top-k. SPLIT=1: hi only — tail.
// OMODE: 0 = NCHW f32 out, 1 = NHWC f16 hi/lo out, 2 = NHWC f32 out.
// 1-D grid, bijective XCD-grouped decode (r9: dcn FETCH 144->36 MB).
// MFMA 16x16x32 f16 (HW-verified r5-r13): A row=l&15 (oc), k=(l>>4)*8+j;
//   B col=l&15 (px); D col=l&15 (px), row=(l>>4)*4+reg (oc).
template<int CIN, int OC, int OCB, int ACT, int OMODE, int SPLIT>
__global__ __launch_bounds__(256)
void conv3x3_mfma_k(const _Float16* __restrict__ iH0, const _Float16* __restrict__ iL0,
                    const _Float16* __restrict__ iH1, const _Float16* __restrict__ iL1, int cin0,
                    const _Float16* __restrict__ wHi, const _Float16* __restrict__ wLo,
                    const float* __restrict__ bias,
                    float* __restrict__ outF, _Float16* __restrict__ oH, _Float16* __restrict__ oL)
{
  constexpr int NOF  = OCB / 16;
  constexpr int NAQ  = (SPLIT == 3) ? NOF : 1;
  constexpr int REC  = (SPLIT == 3) ? 64 : 32;
  constexpr int nOcg = OC / OCB;
  __shared__ _Float16 sB[6 * 34 * REC];   // split3: 26,112 B; split1: 13,056 B

  const int l  = threadIdx.x & 63;
  const int wv = threadIdx.x >> 6;

  const int bid = blockIdx.x;
  const int xcd = bid & 7, q = bid >> 3;
  const int ocg  = q % nOcg;
  const int tIdx = (q / nOcg) * 8 + xcd;
  const int b   = tIdx >> 9;                  // 8 x-tiles * 64 y-tiles = 512/batch
  const int x0  = ((tIdx >> 6) & 7) * 32;
  const int y0  = (tIdx & 63) * 4;
  const int oc0 = ocg * OCB;

  float4v accP[NOF][2];
  float4v accQ[NAQ][2];
  #pragma unroll
  for (int j = 0; j < NOF; ++j)
    #pragma unroll
    for (int f = 0; f < 2; ++f)
      accP[j][f] = (float4v){0.f, 0.f, 0.f, 0.f};
  #pragma unroll
  for (int j = 0; j < NAQ; ++j)
    #pragma unroll
    for (int f = 0; f < 2; ++f)
      accQ[j][f] = (float4v){0.f, 0.f, 0.f, 0.f};

  const int k8  = (l >> 4) * 8;
  const int ocl = l & 15;
  const int rowy = y0 + wv;
  const int sq  = l & 3;          // ci granule (staging)
  const int spx = l >> 2;         // px offset within 16-px subtile (staging)

  #pragma unroll 1
  for (int cc = 0; cc < CIN; cc += 32) {
    const _Float16 *cbH, *cbL;
    if (cc < cin0) {
      size_t o = (size_t)(b * (cin0 >> 5) + (cc >> 5)) * HW * 32;
      cbH = iH0 + o; cbL = iL0 + o;
    } else {
      size_t o = (size_t)(b * ((CIN - cin0) >> 5) + ((cc - cin0) >> 5)) * HW * 32;
      cbH = iH1 + o; cbL = iL1 + o;
    }
    __syncthreads();
    if constexpr (SPLIT == 3) {
      // 36 wave-tasks = 6 rows x {hi,lo} x 3 px-subtiles (3rd partial: px 32,33)
      #pragma unroll 2
      for (int t = wv; t < 36; t += 4) {
        int r = t / 6; int rem = t - r * 6; int bsel = rem / 3; int s = rem - bsel * 3;
        const _Float16* src = bsel ? cbL : cbH;
        int gy = y0 + r - 1;
        bool vy = (gy >= 0) && (gy < H);
        int gyc = gy < 0 ? 0 : (gy >= H ? H - 1 : gy);
        int pxl = s * 16 + spx;
        bool lact = (s < 2) || (l < 8);
        int gx = x0 + pxl - 1;
        bool vx = (gx >= 0) && (gx < W);
        int gxc = gx < 0 ? 0 : (gx >= W ? W - 1 : gx);
        half8v v = h8zero();
        if (lact && vy && vx)
          v = *(const half8v*)&src[((size_t)gyc * W + gxc) * 32 + sq * 8];
        int cls = (sq + (bsel ? 4 : 0)) ^ (pxl & 7);
        if (lact)
          *(half8v*)&sB[(r * 34 + pxl) * 64 + cls * 8] = v;
      }
    } else {
      // 18 wave-tasks = 6 rows x 3 px-subtiles (hi only)
      #pragma unroll 2
      for (int t = wv; t < 18; t += 4) {
        int r = t / 3; int s = t - r * 3;
        int gy = y0 + r - 1;
        bool vy = (gy >= 0) && (gy < H);
        int gyc = gy < 0 ? 0 : (gy >= H ? H - 1 : gy);
        int pxl = s * 16 + spx;
        bool lact = (s < 2) || (l < 8);
        int gx = x0 + pxl - 1;
        bool vx = (gx >= 0) && (gx < W);
        int gxc = gx < 0 ? 0 : (gx >= W ? W - 1 : gx);
        half8v v = h8zero();
        if (lact && vy && vx)
          v = *(const half8v*)&cbH[((size_t)gyc * W + gxc) * 32 + sq * 8];
        int cls = (sq ^ pxl) & 3;
        if (lact)
          *(half8v*)&sB[(r * 34 + pxl) * 32 + cls * 8] = v;
      }
    }
    __syncthreads();

    #pragma unroll 1
    for (int tap = 0; tap < 9; ++tap) {
      const int dy = tap / 3, dx = tap - 3 * (tap / 3);
      // ---- A fragments (weights; L2-hot) ----
      half8v ah[NOF], aq[NAQ];
      const _Float16* hp = wHi + ((size_t)tap * OC + oc0 + ocl) * CIN + cc + k8;
      #pragma unroll
      for (int j = 0; j < NOF; ++j)
        ah[j] = *(const half8v*)(hp + (size_t)j * 16 * CIN);
      if constexpr (SPLIT == 3) {
        const _Float16* lp = wLo + ((size_t)tap * OC + oc0 + ocl) * CIN + cc + k8;
        #pragma unroll
        for (int j = 0; j < NOF; ++j)
          aq[j] = *(const half8v*)(lp + (size_t)j * 16 * CIN);
      }
      // ---- B fragments from LDS + MFMA cluster ----
      const int px = ocl + dx;
      if constexpr (SPLIT == 3) {
        const int rbase = ((wv + dy) * 34 + px) * 64;
        const int clsH = (l >> 4) ^ (px & 7);
        const int clsQ = ((l >> 4) + 4) ^ (px & 7);
        #pragma unroll
        for (int f = 0; f < 2; ++f) {
          half8v bh = *(const half8v*)&sB[rbase + f * 1024 + clsH * 8];
          half8v bq = *(const half8v*)&sB[rbase + f * 1024 + clsQ * 8];
          #pragma unroll
          for (int j = 0; j < NOF; ++j) {
            accP[j][f] = __builtin_amdgcn_mfma_f32_16x16x32_f16(ah[j], bh, accP[j][f], 0, 0, 0);
            accQ[j][f] = __builtin_amdgcn_mfma_f32_16x16x32_f16(ah[j], bq, accQ[j][f], 0, 0, 0);
            accQ[j][f] = __builtin_amdgcn_mfma_f32_16x16x32_f16(aq[j], bh, accQ[j][f], 0, 0, 0);
          }
        }
      } else {
        const int rbase = ((wv + dy) * 34 + px) * 32;
        const int clsH = ((l >> 4) ^ px) & 3;
        #pragma unroll
        for (int f = 0; f < 2; ++f) {
          half8v bh = *(const half8v*)&sB[rbase + f * 512 + clsH * 8];
          #pragma unroll
          for (int j = 0; j < NOF; ++j)
            accP[j][f] = __builtin_amdgcn_mfma_f32_16x16x32_f16(ah[j], bh, accP[j][f], 0, 0, 0);
        }
      }
    }
  }

  // ---- epilogue: D col=l&15 (px), row=(l>>4)*4+reg (oc) ----
  #pragma unroll
  for (int j = 0; j < NOF; ++j)
    #pragma unroll
    for (int f = 0; f < 2; ++f) {
      const int px  = x0 + f * 16 + ocl;
      const int occ = oc0 + j * 16 + (l >> 4) * 4;
      float vv4[4];
      #pragma unroll
      for (int r = 0; r < 4; ++r) {
        float bv = bias ? bias[occ + r] : 0.f;
        float vv = accP[j][f][r] + bv;
        if constexpr (SPLIT == 3) vv += accQ[j][f][r] * (1.0f / 2048.0f);
        vv4[r] = apply_act<ACT>(vv);
      }
      if constexpr (OMODE == 0) {
        #pragma unroll
        for (int r = 0; r < 4; ++r)
          outF[((size_t)(b * OC + occ + r) * H + rowy) * W + px] = vv4[r];
      } else if constexpr (OMODE == 1) {
        __attribute__((aligned(8))) _Float16 hv[4], lv[4];
        #pragma unroll
        for (int r = 0; r < 4; ++r) {
          _Float16 h = (_Float16)vv4[r];
          hv[r] = h;
          lv[r] = (_Float16)((vv4[r] - (float)h) * 2048.0f);
        }
        size_t ob = ((size_t)b * HW + (size_t)rowy * W + px) * OC + occ;
        *(half4v*)&oH[ob] = *(half4v*)&hv[0];
        *(half4v*)&oL[ob] = *(half4v*)&lv[0];
      } else {
        float4 v4;
        v4.x = vv4[0]; v4.y = vv4[1]; v4.z = vv4[2]; v4.w = vv4[3];
        *(float4*)&outF[((size_t)b * HW + (size_t)rowy * W + px) * OC + occ] = v4;
      }
    }
}

// ---------- 1x1 conv: NHWC f32 in -> chunked NHWC f16 out (hi only) ----------
template<int CIN, int OCB, int ACT>
__global__ __launch_bounds__(256)
void conv1x1_nhwc_k(const float* __restrict__ in, const float* __restrict__ w,
                    _Float16* __restrict__ oH, int OC)
{
  __shared__ __align__(16) float sW[OCB][CIN];
  const int b   = blockIdx.y;
  const int oc0 = blockIdx.z * OCB;
  for (int t = threadIdx.x; t < OCB * CIN; t += 256)
    sW[t / CIN][t % CIN] = w[(size_t)(oc0 + t / CIN) * CIN + (t % CIN)];
  __syncthreads();

  const int pb = blockIdx.x * 1024 + threadIdx.x;    // 4 px at stride 256
  float acc[OCB][4];
  #pragma unroll
  for (int o = 0; o < OCB; ++o)
    #pragma unroll
    for (int i = 0; i < 4; ++i) acc[o][i] = 0.f;

  #pragma unroll 1
  for (int c0 = 0; c0 < CIN; c0 += 8) {
    float v[4][8];
    #pragma unroll
    for (int i = 0; i < 4; ++i) {
      const float* ip = in + ((size_t)b * HW + pb + i * 256) * CIN + c0;
      float4 a = *(const float4*)ip;
      float4 c = *(const float4*)(ip + 4);
      v[i][0]=a.x; v[i][1]=a.y; v[i][2]=a.z; v[i][3]=a.w;
      v[i][4]=c.x; v[i][5]=c.y; v[i][6]=c.z; v[i][7]=c.w;
    }
    #pragma unroll
    for (int o = 0; o < OCB; ++o) {
      const float4 w0 = *(const float4*)&sW[o][c0];
      const float4 w1 = *(const float4*)&sW[o][c0 + 4];
      #pragma unroll
      for (int i = 0; i < 4; ++i) {
        acc[o][i] += v[i][0]*w0.x + v[i][1]*w0.y + v[i][2]*w0.z + v[i][3]*w0.w
                   + v[i][4]*w1.x + v[i][5]*w1.y + v[i][6]*w1.z + v[i][7]*w1.w;
      }
    }
  }
  #pragma unroll
  for (int i = 0; i < 4; ++i) {
    __attribute__((aligned(16))) _Float16 hv[OCB];
    #pragma unroll
    for (int o = 0; o < OCB; ++o)
      hv[o] = (_Float16)apply_act<ACT>(acc[o][i]);
    size_t ob = ((size_t)(b * (OC >> 5) + (oc0 >> 5)) * HW + pb + i * 256) * 32 + (oc0 & 31);
    #pragma unroll
    for (int j = 0; j < OCB / 8; ++j)
      *(half8v*)&oH[ob + j * 8] = *(half8v*)&hv[j * 8];
  }
}

// ---------- corr + top-3 (jax tie-break: lower index wins); warp NCHW f32 ----------
__global__ __launch_bounds__(256)
void corr_topk_k(const float* __restrict__ warp, const float* __restrict__ x,
                 int* __restrict__ idxo)
{
  const int p = blockIdx.x * 256 + threadIdx.x;
  const int b = blockIdx.y;
  float corr[9];
  #pragma unroll
  for (int o = 0; o < 9; ++o) corr[o] = 0.f;
  #pragma unroll 2
  for (int c = 0; c < 32; ++c) {
    float xv = x[((size_t)b * 32 + c) * HW + p];
    const float* wp = warp + ((size_t)b * 288 + (size_t)c * 9) * HW + p;
    #pragma unroll
    for (int o = 0; o < 9; ++o) corr[o] += wp[(size_t)o * HW] * xv;
  }
  unsigned mask = 0;
  int packed = 0;
  #pragma unroll
  for (int t = 0; t < 3; ++t) {
    float best = -INFINITY; int bi = 0;
    #pragma unroll
    for (int o = 0; o < 9; ++o) {
      bool take = (((mask >> o) & 1u) == 0u) && (corr[o] > best);
      best = take ? corr[o] : best;
      bi   = take ? o       : bi;
    }
    mask   |= 1u << bi;
    packed |= bi << (4 * t);
  }
  idxo[(size_t)b * HW + p] = packed;
}

// ---------- gather selected warps + 3x3 conv with w_sel; out 32-ch NHWC f16 (hi only) ----------
__global__ __launch_bounds__(256)
void selconv_k(const float* __restrict__ warp, const int* __restrict__ idxp,
               const float* __restrict__ wsel, const float* __restrict__ bsel,
               _Float16* __restrict__ oH)
{
  const int tx = threadIdx.x & 31, ty = threadIdx.x >> 5;
  const int px = blockIdx.x * 32 + tx;
  const int py = blockIdx.y * 8 + ty;
  const int b  = blockIdx.z;

  int  nidx[9];
  bool nval[9];
  int  qoff[9];
  #pragma unroll
  for (int kh = 0; kh < 3; ++kh)
    #pragma unroll
    for (int kw = 0; kw < 3; ++kw) {
      int k = kh * 3 + kw;
      int qy = py + kh - 1, qx = px + kw - 1;
      nval[k] = (qy >= 0 && qy < H && qx >= 0 && qx < W);
      qoff[k] = qy * W + qx;
      nidx[k] = nval[k] ? idxp[(size_t)b * HW + qoff[k]] : 0;
    }

  float ws27[27];
  #pragma unroll
  for (int i = 0; i < 27; ++i) ws27[i] = wsel[i];
  const float bs = bsel[0];

  float arr[32];
  #pragma unroll 1
  for (int c = 0; c < 32; ++c) {
    float acc = bs;
    const float* wb = warp + ((size_t)b * 288 + (size_t)c * 9) * HW;
    #pragma unroll
    for (int k = 0; k < 9; ++k) {
      if (nval[k]) {
        int pk = nidx[k];
        #pragma unroll
        for (int t = 0; t < 3; ++t) {
          int o = (pk >> (4 * t)) & 15;
          acc += ws27[t * 9 + k] * wb[(size_t)o * HW + qoff[k]];
        }
      }
    }
    arr[c] = acc;
  }

  __attribute__((aligned(16))) _Float16 hv[32];
  #pragma unroll
  for (int c = 0; c < 32; ++c) hv[c] = (_Float16)arr[c];
  size_t ob = ((size_t)b * HW + (size_t)py * W + px) * 32;
  #pragma unroll
  for (int j = 0; j < 4; ++j)
    *(half8v*)&oH[ob + j * 8] = *(half8v*)&hv[j * 8];
}

// ---------- launch ----------
extern "C" void kernel_launch(void* const* d_in, const int* in_sizes, int n_in,
                              void* d_out, int out_size, void* d_ws, size_t ws_size,
                              hipStream_t stream) {
  const float* x      = (const float*)d_in[0];
  const float* key    = (const float*)d_in[1];
  const float* w_off1 = (const float*)d_in[2];
  const float* b_off1 = (const float*)d_in[3];
  const float* w_off2 = (const float*)d_in[4];
  const float* b_off2 = (const float*)d_in[5];
  const float* w_dcn  = (const float*)d_in[6];
  const float* b_dcn  = (const float*)d_in[7];
  const float* w_sel  = (const float*)d_in[8];
  const float* b_sel  = (const float*)d_in[9];
  const float* w_t1   = (const float*)d_in[10];
  const float* w_t2   = (const float*)d_in[11];
  const float* w_t3   = (const float*)d_in[12];
  const float* w_t4   = (const float*)d_in[13];
  const float* w_t5   = (const float*)d_in[14];

  // ---- workspace layout (peak ~185.2 MB; proven safe r5-r13) ----
  char* ws = (char*)d_ws;
  float* warp = (float*)(ws);                                // [2,288,HW] f32 NCHW, 144 MiB
  // pre-dcn scratch inside warp region (dead before dcn writes):
  _Float16* xH  = (_Float16*)(ws);                           // 8 MiB
  _Float16* xL  = (_Float16*)(ws + 8388608);
  _Float16* o1H = (_Float16*)(ws + 16777216);                // off1 out, 8+8 MiB
  _Float16* o1L = (_Float16*)(ws + 25165824);
  _Float16* w1H = (_Float16*)(ws + 33554432);                // off1/off2 weight tables
  _Float16* w1L = w1H + 18432;
  _Float16* w2H = w1L + 18432;
  _Float16* w2L = w2H + 9216;
  // outside warp region:
  _Float16* kH  = (_Float16*)(ws + 150994944);               // key pack, 8+8 MiB
  _Float16* kL  = (_Float16*)(ws + 159383552);
  _Float16* o2H = (_Float16*)(ws + 167772160);               // off2 out, 8+8 MiB
  _Float16* o2L = (_Float16*)(ws + 176160768);
  _Float16* wdH = (_Float16*)(ws + 184549376);               // dcn tables (165888 each)
  _Float16* wdL = wdH + 165888;                              // ends ~185.2 MB
  // post-dcn:
  int*      idxb = (int*)(ws + 150994944);                   // 0.5 MiB (over kH, dead)
  _Float16* kwH  = (_Float16*)(ws + 159383552);              // selconv out hi (over kL)
  _Float16* twB  = (_Float16*)(ws + 176160768);              // tail tables (over o2L)
  _Float16* t1H_w = twB;
  _Float16* t1L_w = twB + 9216;
  _Float16* t3H_w = twB + 18432;
  _Float16* t3L_w = twB + 165888;
  _Float16* t5H_w = twB + 313344;
  _Float16* t5L_w = twB + 322560;
  // tail activations inside dead warp region:
  float*    y1  = (float*)(ws);                              // t1 out NHWC f32 [2,HW,32], 16 MiB
  _Float16* t2H = (_Float16*)(ws + 16777216);                // chunked [2,4,HW,32], 32 MiB
  float*    y3  = (float*)(ws + 83886080);                   // t3 out NHWC f32 [2,HW,128], 64 MiB
  _Float16* t4H = (_Float16*)(ws + 50331648);                // 8 MiB
  float* out = (float*)d_out;

  dim3 blk(256);

  // pack x,key -> chunked f16 hi/lo (one launch)
  pack2_k<<<dim3(256, 2, 2), blk, 0, stream>>>(x, xH, xL, key, kH, kL);
  // phase-1 weight tables (one launch: off1 72 blk, off2 36 blk, dcn 648 blk)
  prep3_w_k<<<dim3(756), blk, 0, stream>>>(
      w_off1, w1H, w1L, 32, 64, 72,
      w_off2, w2H, w2L, 32, 32, 36,
      w_dcn,  wdH, wdL, 288, 64);

  // off1 = lrelu(conv(concat(x,key)))  -> f16 hi/lo   [split-3, pre-topk]
  conv3x3_mfma_k<64, 32, 32, 1, 1, 3><<<dim3(1024), blk, 0, stream>>>(
      xH, xL, kH, kL, 32, w1H, w1L, b_off1, nullptr, o1H, o1L);
  // off2 = lrelu(conv(off1))           -> f16 hi/lo   [split-3]
  conv3x3_mfma_k<32, 32, 32, 1, 1, 3><<<dim3(1024), blk, 0, stream>>>(
      o1H, o1L, o1H, o1L, 32, w2H, w2L, b_off2, nullptr, o2H, o2L);
  // warp = conv(concat(key,off2))      -> NCHW f32    [split-3, OCB=32]
  conv3x3_mfma_k<64, 288, 32, 0, 0, 3><<<dim3(9216), blk, 0, stream>>>(
      kH, kL, o2H, o2L, 32, wdH, wdL, b_dcn, warp, nullptr, nullptr);
  // corr + top-3
  corr_topk_k<<<dim3(256, 2), blk, 0, stream>>>(warp, x, idxb);
  // key_warp -> f16 hi (tail is single-f16; lo unused)
  selconv_k<<<dim3(8, 32, 2), blk, 0, stream>>>(warp, idxb, w_sel, b_sel, kwH);

  // phase-2 weight tables (one launch: t1 36, t3 576, t5 36)
  prep3_w_k<<<dim3(648), blk, 0, stream>>>(
      w_t1, t1H_w, t1L_w, 32, 32, 36,
      w_t3, t3H_w, t3L_w, 128, 128, 576,
      w_t5, t5H_w, t5L_w, 32, 32);

  // t1: conv3x3 (gelu) -> NHWC f32 y1            [single-f16]
  conv3x3_mfma_k<32, 32, 32, 2, 2, 1><<<dim3(1024), blk, 0, stream>>>(
      kwH, kwH, kwH, kwH, 32, t1H_w, t1L_w, nullptr, y1, nullptr, nullptr);
  // t2: 1x1 (gelu) -> chunked f16 hi [2,4,HW,32]
  conv1x1_nhwc_k<32, 16, 2><<<dim3(64, 2, 8), blk, 0, stream>>>(y1, w_t2, t2H, 128);
  // t3: conv3x3 (gelu) -> NHWC f32 y3            [single-f16, OCB=64]
  conv3x3_mfma_k<128, 128, 64, 2, 2, 1><<<dim3(2048), blk, 0, stream>>>(
      t2H, t2H, t2H, t2H, 128, t3H_w, t3L_w, nullptr, y3, nullptr, nullptr);
  // t4: 1x1 (gelu) -> f16 hi
  conv1x1_nhwc_k<128, 16, 2><<<dim3(64, 2, 2), blk, 0, stream>>>(y3, w_t4, t4H, 32);
  // t5: conv3x3 -> NCHW f32 final                [single-f16]
  conv3x3_mfma_k<32, 32, 32, 0, 0, 1><<<dim3(1024), blk, 0, stream>>>(
      t4H, t4H, t4H, t4H, 32, t5H_w, t5L_w, nullptr, out, nullptr, nullptr);
}

// Round 15
// 692.598 us; speedup vs baseline: 1.2427x; 1.2427x over previous
//
#include <hip/hip_runtime.h>
#include <math.h>

static constexpr int H = 256, W = 256, HW = H * W;

typedef __attribute__((ext_vector_type(8))) _Float16 half8v;  // 16B
typedef __attribute__((ext_vector_type(4))) _Float16 half4v;  // 8B
typedef __attribute__((ext_vector_type(4))) float  float4v;   // MFMA acc

__device__ __forceinline__ half8v h8zero() {
  half8v z;
  #pragma unroll
  for (int i = 0; i < 8; ++i) z[i] = (_Float16)0;
  return z;
}

// ---------- activations ----------
__device__ __forceinline__ float gelu_f(float v) {
  return 0.5f * v * (1.0f + erff(v * 0.70710678118654752440f));
}
template<int ACT>
__device__ __forceinline__ float apply_act(float v) {
  if constexpr (ACT == 1) return v >= 0.f ? v : 0.1f * v;   // LeakyReLU(0.1)
  if constexpr (ACT == 2) return gelu_f(v);
  return v;
}

// ---------- pack both inputs: NCHW f32 (C=32) -> chunked NHWC f16 hi + scaled lo ----------
__global__ __launch_bounds__(256)
void pack2_k(const float* __restrict__ inA, _Float16* __restrict__ hiA, _Float16* __restrict__ loA,
             const float* __restrict__ inB, _Float16* __restrict__ hiB, _Float16* __restrict__ loB)
{
  const int p = blockIdx.x * 256 + threadIdx.x;
  const int b = blockIdx.y;
  const float* in = blockIdx.z ? inB : inA;
  _Float16* hi = blockIdx.z ? hiB : hiA;
  _Float16* lo = blockIdx.z ? loB : loA;
  const float* ip = in + (size_t)b * 32 * HW + p;
  __attribute__((aligned(16))) _Float16 hv[32], lv[32];
  #pragma unroll
  for (int c = 0; c < 32; ++c) {
    float v = ip[(size_t)c * HW];
    _Float16 h = (_Float16)v;
    hv[c] = h;
    lv[c] = (_Float16)((v - (float)h) * 2048.0f);
  }
  size_t ob = ((size_t)b * HW + p) * 32;
  #pragma unroll
  for (int j = 0; j < 4; ++j) {
    *(half8v*)&hi[ob + j * 8] = *(half8v*)&hv[j * 8];
    *(half8v*)&lo[ob + j * 8] = *(half8v*)&lv[j * 8];
  }
}

// ---------- weight prep x3: [OC][CIN][3][3] f32 -> [tap][OC][CIN] f16 hi + scaled lo ----------
__device__ __forceinline__ void prep_w_body(const float* w, _Float16* hi, _Float16* lo,
                                            int OC, int CIN, int tid)
{
  if (tid >= OC * CIN * 9) return;
  int ci = tid % CIN; int r = tid / CIN; int oc = r % OC; int tap = r / OC;
  float v = w[((size_t)oc * CIN + ci) * 9 + tap];
  _Float16 h = (_Float16)v;
  hi[tid] = h;
  lo[tid] = (_Float16)((v - (float)h) * 2048.0f);
}
__global__ __launch_bounds__(256)
void prep3_w_k(const float* __restrict__ w0, _Float16* __restrict__ h0, _Float16* __restrict__ l0, int OC0, int CIN0, int nb0,
               const float* __restrict__ w1, _Float16* __restrict__ h1, _Float16* __restrict__ l1, int OC1, int CIN1, int nb1,
               const float* __restrict__ w2, _Float16* __restrict__ h2, _Float16* __restrict__ l2, int OC2, int CIN2)
{
  int bb = blockIdx.x;
  if (bb < nb0)            prep_w_body(w0, h0, l0, OC0, CIN0, bb * 256 + threadIdx.x);
  else if (bb < nb0 + nb1) prep_w_body(w1, h1, l1, OC1, CIN1, (bb - nb0) * 256 + threadIdx.x);
  else                     prep_w_body(w2, h2, l2, OC2, CIN2, (bb - nb0 - nb1) * 256 + threadIdx.x);
}

// ---------- 3x3 conv, f16 MFMA; r10-proven structure (best total: 718 us) ----------
// Full LDS staging (hi+lo for SPLIT=3), 64-px F=4 wave tile, per-tap weight
// loads from global (L2-hot). No manual pipelining (r13 regression), no narrow
// tile (r14 regression), occupancy-insensitive plateau established r8-r14.
// SPLIT=3: split-3 (accP + accQ/2048) — pre-top-k. SPLIT=1: hi only — tail.
// OMODE: 0 = NCHW f32 out, 1 = NHWC f16 hi/lo out, 2 = NHWC f32 out.
// 1-D grid, bijective XCD-grouped decode (r9: dcn FETCH 144->36 MB).
// MFMA 16x16x32 f16 (HW-verified r5-r14): A row=l&15 (oc), k=(l>>4)*8+j;
//   B col=l&15 (px); D col=l&15 (px), row=(l>>4)*4+reg (oc).
template<int CIN, int OC, int OCB, int ACT, int OMODE, int SPLIT>
__global__ __launch_bounds__(256)
void conv3x3_mfma_k(const _Float16* __restrict__ iH0, const _Float16* __restrict__ iL0,
                    const _Float16* __restrict__ iH1, const _Float16* __restrict__ iL1, int cin0,
                    const _Float16* __restrict__ wHi, const _Float16* __restrict__ wLo,
                    const float* __restrict__ bias,
                    float* __restrict__ outF, _Float16* __restrict__ oH, _Float16* __restrict__ oL)
{
  constexpr int NOF  = OCB / 16;
  constexpr int NAQ  = (SPLIT == 3) ? NOF : 1;
  constexpr int REC  = (SPLIT == 3) ? 64 : 32;
  constexpr int nOcg = OC / OCB;
  __shared__ _Float16 sB[6 * 66 * REC];

  const int l  = threadIdx.x & 63;
  const int wv = threadIdx.x >> 6;

  const int bid = blockIdx.x;
  const int xcd = bid & 7, q = bid >> 3;
  const int ocg  = q % nOcg;
  const int tIdx = (q / nOcg) * 8 + xcd;
  const int b   = tIdx >> 8;
  const int x0  = ((tIdx >> 6) & 3) * 64;
  const int y0  = (tIdx & 63) * 4;
  const int oc0 = ocg * OCB;

  float4v accP[NOF][4];
  float4v accQ[NAQ][4];
  #pragma unroll
  for (int j = 0; j < NOF; ++j)
    #pragma unroll
    for (int f = 0; f < 4; ++f)
      accP[j][f] = (float4v){0.f, 0.f, 0.f, 0.f};
  #pragma unroll
  for (int j = 0; j < NAQ; ++j)
    #pragma unroll
    for (int f = 0; f < 4; ++f)
      accQ[j][f] = (float4v){0.f, 0.f, 0.f, 0.f};

  const int k8  = (l >> 4) * 8;
  const int ocl = l & 15;
  const int rowy = y0 + wv;
  const int sq  = l & 3;          // ci granule (staging)
  const int spx = l >> 2;         // px offset within 16-px subtile (staging)

  #pragma unroll 1
  for (int cc = 0; cc < CIN; cc += 32) {
    const _Float16 *cbH, *cbL;
    if (cc < cin0) {
      size_t o = (size_t)(b * (cin0 >> 5) + (cc >> 5)) * HW * 32;
      cbH = iH0 + o; cbL = iL0 + o;
    } else {
      size_t o = (size_t)(b * ((CIN - cin0) >> 5) + ((cc - cin0) >> 5)) * HW * 32;
      cbH = iH1 + o; cbL = iL1 + o;
    }
    __syncthreads();
    if constexpr (SPLIT == 3) {
      // 60 wave-tasks = 6 rows x {hi,lo} x 5 px-subtiles
      #pragma unroll 2
      for (int t = wv; t < 60; t += 4) {
        int r = t / 10; int rem = t - r * 10; int bsel = rem / 5; int s = rem - bsel * 5;
        const _Float16* src = bsel ? cbL : cbH;
        int gy = y0 + r - 1;
        bool vy = (gy >= 0) && (gy < H);
        int gyc = gy < 0 ? 0 : (gy >= H ? H - 1 : gy);
        int pxl = s * 16 + spx;
        bool lact = (s < 4) || (l < 8);
        int gx = x0 + pxl - 1;
        bool vx = (gx >= 0) && (gx < W);
        int gxc = gx < 0 ? 0 : (gx >= W ? W - 1 : gx);
        half8v v = h8zero();
        if (lact && vy && vx)
          v = *(const half8v*)&src[((size_t)gyc * W + gxc) * 32 + sq * 8];
        int cls = (sq + (bsel ? 4 : 0)) ^ (pxl & 7);
        if (lact)
          *(half8v*)&sB[(r * 66 + pxl) * 64 + cls * 8] = v;
      }
    } else {
      // 30 wave-tasks = 6 rows x 5 px-subtiles (hi only)
      #pragma unroll 2
      for (int t = wv; t < 30; t += 4) {
        int r = t / 5; int s = t - r * 5;
        int gy = y0 + r - 1;
        bool vy = (gy >= 0) && (gy < H);
        int gyc = gy < 0 ? 0 : (gy >= H ? H - 1 : gy);
        int pxl = s * 16 + spx;
        bool lact = (s < 4) || (l < 8);
        int gx = x0 + pxl - 1;
        bool vx = (gx >= 0) && (gx < W);
        int gxc = gx < 0 ? 0 : (gx >= W ? W - 1 : gx);
        half8v v = h8zero();
        if (lact && vy && vx)
          v = *(const half8v*)&cbH[((size_t)gyc * W + gxc) * 32 + sq * 8];
        int cls = (sq ^ pxl) & 3;
        if (lact)
          *(half8v*)&sB[(r * 66 + pxl) * 32 + cls * 8] = v;
      }
    }
    __syncthreads();

    #pragma unroll 1
    for (int tap = 0; tap < 9; ++tap) {
      const int dy = tap / 3, dx = tap - 3 * (tap / 3);
      half8v ah[NOF], aq[NAQ];
      const _Float16* hp = wHi + ((size_t)tap * OC + oc0 + ocl) * CIN + cc + k8;
      #pragma unroll
      for (int j = 0; j < NOF; ++j)
        ah[j] = *(const half8v*)(hp + (size_t)j * 16 * CIN);
      if constexpr (SPLIT == 3) {
        const _Float16* lp = wLo + ((size_t)tap * OC + oc0 + ocl) * CIN + cc + k8;
        #pragma unroll
        for (int j = 0; j < NOF; ++j)
          aq[j] = *(const half8v*)(lp + (size_t)j * 16 * CIN);
      }
      const int px = ocl + dx;
      if constexpr (SPLIT == 3) {
        const int rbase = ((wv + dy) * 66 + px) * 64;
        const int clsH = (l >> 4) ^ (px & 7);
        const int clsQ = ((l >> 4) + 4) ^ (px & 7);
        #pragma unroll
        for (int f = 0; f < 4; ++f) {
          half8v bh = *(const half8v*)&sB[rbase + f * 1024 + clsH * 8];
          half8v bq = *(const half8v*)&sB[rbase + f * 1024 + clsQ * 8];
          #pragma unroll
          for (int j = 0; j < NOF; ++j) {
            accP[j][f] = __builtin_amdgcn_mfma_f32_16x16x32_f16(ah[j], bh, accP[j][f], 0, 0, 0);
            accQ[j][f] = __builtin_amdgcn_mfma_f32_16x16x32_f16(ah[j], bq, accQ[j][f], 0, 0, 0);
            accQ[j][f] = __builtin_amdgcn_mfma_f32_16x16x32_f16(aq[j], bh, accQ[j][f], 0, 0, 0);
          }
        }
      } else {
        const int rbase = ((wv + dy) * 66 + px) * 32;
        const int clsH = ((l >> 4) ^ px) & 3;
        #pragma unroll
        for (int f = 0; f < 4; ++f) {
          half8v bh = *(const half8v*)&sB[rbase + f * 512 + clsH * 8];
          #pragma unroll
          for (int j = 0; j < NOF; ++j)
            accP[j][f] = __builtin_amdgcn_mfma_f32_16x16x32_f16(ah[j], bh, accP[j][f], 0, 0, 0);
        }
      }
    }
  }

  // ---- epilogue: D col=l&15 (px), row=(l>>4)*4+reg (oc) ----
  #pragma unroll
  for (int j = 0; j < NOF; ++j)
    #pragma unroll
    for (int f = 0; f < 4; ++f) {
      const int px  = x0 + f * 16 + ocl;
      const int occ = oc0 + j * 16 + (l >> 4) * 4;
      float vv4[4];
      #pragma unroll
      for (int r = 0; r < 4; ++r) {
        float bv = bias ? bias[occ + r] : 0.f;
        float vv = accP[j][f][r] + bv;
        if constexpr (SPLIT == 3) vv += accQ[j][f][r] * (1.0f / 2048.0f);
        vv4[r] = apply_act<ACT>(vv);
      }
      if constexpr (OMODE == 0) {
        #pragma unroll
        for (int r = 0; r < 4; ++r)
          outF[((size_t)(b * OC + occ + r) * H + rowy) * W + px] = vv4[r];
      } else if constexpr (OMODE == 1) {
        __attribute__((aligned(8))) _Float16 hv[4], lv[4];
        #pragma unroll
        for (int r = 0; r < 4; ++r) {
          _Float16 h = (_Float16)vv4[r];
          hv[r] = h;
          lv[r] = (_Float16)((vv4[r] - (float)h) * 2048.0f);
        }
        size_t ob = ((size_t)b * HW + (size_t)rowy * W + px) * OC + occ;
        *(half4v*)&oH[ob] = *(half4v*)&hv[0];
        *(half4v*)&oL[ob] = *(half4v*)&lv[0];
      } else {
        float4 v4;
        v4.x = vv4[0]; v4.y = vv4[1]; v4.z = vv4[2]; v4.w = vv4[3];
        *(float4*)&outF[((size_t)b * HW + (size_t)rowy * W + px) * OC + occ] = v4;
      }
    }
}

// ---------- 1x1 conv: NHWC f32 in -> chunked NHWC f16 out (hi only) ----------
template<int CIN, int OCB, int ACT>
__global__ __launch_bounds__(256)
void conv1x1_nhwc_k(const float* __restrict__ in, const float* __restrict__ w,
                    _Float16* __restrict__ oH, int OC)
{
  __shared__ __align__(16) float sW[OCB][CIN];
  const int b   = blockIdx.y;
  const int oc0 = blockIdx.z * OCB;
  for (int t = threadIdx.x; t < OCB * CIN; t += 256)
    sW[t / CIN][t % CIN] = w[(size_t)(oc0 + t / CIN) * CIN + (t % CIN)];
  __syncthreads();

  const int pb = blockIdx.x * 1024 + threadIdx.x;    // 4 px at stride 256
  float acc[OCB][4];
  #pragma unroll
  for (int o = 0; o < OCB; ++o)
    #pragma unroll
    for (int i = 0; i < 4; ++i) acc[o][i] = 0.f;

  #pragma unroll 1
  for (int c0 = 0; c0 < CIN; c0 += 8) {
    float v[4][8];
    #pragma unroll
    for (int i = 0; i < 4; ++i) {
      const float* ip = in + ((size_t)b * HW + pb + i * 256) * CIN + c0;
      float4 a = *(const float4*)ip;
      float4 c = *(const float4*)(ip + 4);
      v[i][0]=a.x; v[i][1]=a.y; v[i][2]=a.z; v[i][3]=a.w;
      v[i][4]=c.x; v[i][5]=c.y; v[i][6]=c.z; v[i][7]=c.w;
    }
    #pragma unroll
    for (int o = 0; o < OCB; ++o) {
      const float4 w0 = *(const float4*)&sW[o][c0];
      const float4 w1 = *(const float4*)&sW[o][c0 + 4];
      #pragma unroll
      for (int i = 0; i < 4; ++i) {
        acc[o][i] += v[i][0]*w0.x + v[i][1]*w0.y + v[i][2]*w0.z + v[i][3]*w0.w
                   + v[i][4]*w1.x + v[i][5]*w1.y + v[i][6]*w1.z + v[i][7]*w1.w;
      }
    }
  }
  #pragma unroll
  for (int i = 0; i < 4; ++i) {
    __attribute__((aligned(16))) _Float16 hv[OCB];
    #pragma unroll
    for (int o = 0; o < OCB; ++o)
      hv[o] = (_Float16)apply_act<ACT>(acc[o][i]);
    size_t ob = ((size_t)(b * (OC >> 5) + (oc0 >> 5)) * HW + pb + i * 256) * 32 + (oc0 & 31);
    #pragma unroll
    for (int j = 0; j < OCB / 8; ++j)
      *(half8v*)&oH[ob + j * 8] = *(half8v*)&hv[j * 8];
  }
}

// ---------- corr + top-3, 4 px/thread float4 (jax tie-break: lower index wins) ----------
__global__ __launch_bounds__(256)
void corr_topk_k(const float* __restrict__ warp, const float* __restrict__ x,
                 int* __restrict__ idxo)
{
  const int p4 = (blockIdx.x * 256 + threadIdx.x) * 4;
  const int b = blockIdx.y;
  float corr[9][4];
  #pragma unroll
  for (int o = 0; o < 9; ++o)
    #pragma unroll
    for (int i = 0; i < 4; ++i) corr[o][i] = 0.f;
  #pragma unroll 1
  for (int c = 0; c < 32; ++c) {
    float4 xv = *(const float4*)&x[((size_t)b * 32 + c) * HW + p4];
    const float* wp = warp + ((size_t)b * 288 + (size_t)c * 9) * HW + p4;
    #pragma unroll
    for (int o = 0; o < 9; ++o) {
      float4 wv = *(const float4*)&wp[(size_t)o * HW];
      corr[o][0] += wv.x * xv.x;
      corr[o][1] += wv.y * xv.y;
      corr[o][2] += wv.z * xv.z;
      corr[o][3] += wv.w * xv.w;
    }
  }
  int4 packs;
  #pragma unroll
  for (int i = 0; i < 4; ++i) {
    unsigned mask = 0;
    int packed = 0;
    #pragma unroll
    for (int t = 0; t < 3; ++t) {
      float best = -INFINITY; int bi = 0;
      #pragma unroll
      for (int o = 0; o < 9; ++o) {
        bool take = (((mask >> o) & 1u) == 0u) && (corr[o][i] > best);
        best = take ? corr[o][i] : best;
        bi   = take ? o          : bi;
      }
      mask   |= 1u << bi;
      packed |= bi << (4 * t);
    }
    ((int*)&packs)[i] = packed;
  }
  *(int4*)&idxo[(size_t)b * HW + p4] = packs;
}

// ---------- gather selected warps + 3x3 conv with w_sel; out 32-ch NHWC f16 (hi only) ----------
__global__ __launch_bounds__(256)
void selconv_k(const float* __restrict__ warp, const int* __restrict__ idxp,
               const float* __restrict__ wsel, const float* __restrict__ bsel,
               _Float16* __restrict__ oH)
{
  const int tx = threadIdx.x & 31, ty = threadIdx.x >> 5;
  const int px = blockIdx.x * 32 + tx;
  const int py = blockIdx.y * 8 + ty;
  const int b  = blockIdx.z;

  int  nidx[9];
  bool nval[9];
  int  qoff[9];
  #pragma unroll
  for (int kh = 0; kh < 3; ++kh)
    #pragma unroll
    for (int kw = 0; kw < 3; ++kw) {
      int k = kh * 3 + kw;
      int qy = py + kh - 1, qx = px + kw - 1;
      nval[k] = (qy >= 0 && qy < H && qx >= 0 && qx < W);
      qoff[k] = qy * W + qx;
      nidx[k] = nval[k] ? idxp[(size_t)b * HW + qoff[k]] : 0;
    }

  float ws27[27];
  #pragma unroll
  for (int i = 0; i < 27; ++i) ws27[i] = wsel[i];
  const float bs = bsel[0];

  float arr[32];
  #pragma unroll 1
  for (int c = 0; c < 32; ++c) {
    float acc = bs;
    const float* wb = warp + ((size_t)b * 288 + (size_t)c * 9) * HW;
    #pragma unroll
    for (int k = 0; k < 9; ++k) {
      if (nval[k]) {
        int pk = nidx[k];
        #pragma unroll
        for (int t = 0; t < 3; ++t) {
          int o = (pk >> (4 * t)) & 15;
          acc += ws27[t * 9 + k] * wb[(size_t)o * HW + qoff[k]];
        }
      }
    }
    arr[c] = acc;
  }

  __attribute__((aligned(16))) _Float16 hv[32];
  #pragma unroll
  for (int c = 0; c < 32; ++c) hv[c] = (_Float16)arr[c];
  size_t ob = ((size_t)b * HW + (size_t)py * W + px) * 32;
  #pragma unroll
  for (int j = 0; j < 4; ++j)
    *(half8v*)&oH[ob + j * 8] = *(half8v*)&hv[j * 8];
}

// ---------- launch ----------
extern "C" void kernel_launch(void* const* d_in, const int* in_sizes, int n_in,
                              void* d_out, int out_size, void* d_ws, size_t ws_size,
                              hipStream_t stream) {
  const float* x      = (const float*)d_in[0];
  const float* key    = (const float*)d_in[1];
  const float* w_off1 = (const float*)d_in[2];
  const float* b_off1 = (const float*)d_in[3];
  const float* w_off2 = (const float*)d_in[4];
  const float* b_off2 = (const float*)d_in[5];
  const float* w_dcn  = (const float*)d_in[6];
  const float* b_dcn  = (const float*)d_in[7];
  const float* w_sel  = (const float*)d_in[8];
  const float* b_sel  = (const float*)d_in[9];
  const float* w_t1   = (const float*)d_in[10];
  const float* w_t2   = (const float*)d_in[11];
  const float* w_t3   = (const float*)d_in[12];
  const float* w_t4   = (const float*)d_in[13];
  const float* w_t5   = (const float*)d_in[14];

  // ---- workspace layout (peak ~185.2 MB; proven safe r5-r14) ----
  char* ws = (char*)d_ws;
  float* warp = (float*)(ws);                                // [2,288,HW] f32 NCHW, 144 MiB
  // pre-dcn scratch inside warp region (dead before dcn writes):
  _Float16* xH  = (_Float16*)(ws);                           // 8 MiB
  _Float16* xL  = (_Float16*)(ws + 8388608);
  _Float16* o1H = (_Float16*)(ws + 16777216);                // off1 out, 8+8 MiB
  _Float16* o1L = (_Float16*)(ws + 25165824);
  _Float16* w1H = (_Float16*)(ws + 33554432);                // off1/off2 weight tables
  _Float16* w1L = w1H + 18432;
  _Float16* w2H = w1L + 18432;
  _Float16* w2L = w2H + 9216;
  // outside warp region:
  _Float16* kH  = (_Float16*)(ws + 150994944);               // key pack, 8+8 MiB
  _Float16* kL  = (_Float16*)(ws + 159383552);
  _Float16* o2H = (_Float16*)(ws + 167772160);               // off2 out, 8+8 MiB
  _Float16* o2L = (_Float16*)(ws + 176160768);
  _Float16* wdH = (_Float16*)(ws + 184549376);               // dcn tables (165888 each)
  _Float16* wdL = wdH + 165888;                              // ends ~185.2 MB
  // post-dcn:
  int*      idxb = (int*)(ws + 150994944);                   // 0.5 MiB (over kH, dead)
  _Float16* kwH  = (_Float16*)(ws + 159383552);              // selconv out hi (over kL)
  _Float16* twB  = (_Float16*)(ws + 176160768);              // tail tables (over o2L)
  _Float16* t1H_w = twB;
  _Float16* t1L_w = twB + 9216;
  _Float16* t3H_w = twB + 18432;
  _Float16* t3L_w = twB + 165888;
  _Float16* t5H_w = twB + 313344;
  _Float16* t5L_w = twB + 322560;
  // tail activations inside dead warp region:
  float*    y1  = (float*)(ws);                              // t1 out NHWC f32 [2,HW,32], 16 MiB
  _Float16* t2H = (_Float16*)(ws + 16777216);                // chunked [2,4,HW,32], 32 MiB
  float*    y3  = (float*)(ws + 83886080);                   // t3 out NHWC f32 [2,HW,128], 64 MiB
  _Float16* t4H = (_Float16*)(ws + 50331648);                // 8 MiB
  float* out = (float*)d_out;

  dim3 blk(256);

  // pack x,key -> chunked f16 hi/lo (one launch)
  pack2_k<<<dim3(256, 2, 2), blk, 0, stream>>>(x, xH, xL, key, kH, kL);
  // phase-1 weight tables (one launch: off1 72 blk, off2 36 blk, dcn 648 blk)
  prep3_w_k<<<dim3(756), blk, 0, stream>>>(
      w_off1, w1H, w1L, 32, 64, 72,
      w_off2, w2H, w2L, 32, 32, 36,
      w_dcn,  wdH, wdL, 288, 64);

  // off1 = lrelu(conv(concat(x,key)))  -> f16 hi/lo   [split-3, pre-topk]
  conv3x3_mfma_k<64, 32, 32, 1, 1, 3><<<dim3(512), blk, 0, stream>>>(
      xH, xL, kH, kL, 32, w1H, w1L, b_off1, nullptr, o1H, o1L);
  // off2 = lrelu(conv(off1))           -> f16 hi/lo   [split-3]
  conv3x3_mfma_k<32, 32, 32, 1, 1, 3><<<dim3(512), blk, 0, stream>>>(
      o1H, o1L, o1H, o1L, 32, w2H, w2L, b_off2, nullptr, o2H, o2L);
  // warp = conv(concat(key,off2))      -> NCHW f32    [split-3, OCB=32]
  conv3x3_mfma_k<64, 288, 32, 0, 0, 3><<<dim3(4608), blk, 0, stream>>>(
      kH, kL, o2H, o2L, 32, wdH, wdL, b_dcn, warp, nullptr, nullptr);
  // corr + top-3 (4 px/thread, float4)
  corr_topk_k<<<dim3(64, 2), blk, 0, stream>>>(warp, x, idxb);
  // key_warp -> f16 hi (tail is single-f16; lo unused)
  selconv_k<<<dim3(8, 32, 2), blk, 0, stream>>>(warp, idxb, w_sel, b_sel, kwH);

  // phase-2 weight tables (one launch: t1 36, t3 576, t5 36)
  prep3_w_k<<<dim3(648), blk, 0, stream>>>(
      w_t1, t1H_w, t1L_w, 32, 32, 36,
      w_t3, t3H_w, t3L_w, 128, 128, 576,
      w_t5, t5H_w, t5L_w, 32, 32);

  // t1: conv3x3 (gelu) -> NHWC f32 y1            [single-f16]
  conv3x3_mfma_k<32, 32, 32, 2, 2, 1><<<dim3(512), blk, 0, stream>>>(
      kwH, kwH, kwH, kwH, 32, t1H_w, t1L_w, nullptr, y1, nullptr, nullptr);
  // t2: 1x1 (gelu) -> chunked f16 hi [2,4,HW,32]
  conv1x1_nhwc_k<32, 16, 2><<<dim3(64, 2, 8), blk, 0, stream>>>(y1, w_t2, t2H, 128);
  // t3: conv3x3 (gelu) -> NHWC f32 y3            [single-f16, OCB=64]
  conv3x3_mfma_k<128, 128, 64, 2, 2, 1><<<dim3(1024), blk, 0, stream>>>(
      t2H, t2H, t2H, t2H, 128, t3H_w, t3L_w, nullptr, y3, nullptr, nullptr);
  // t4: 1x1 (gelu) -> f16 hi
  conv1x1_nhwc_k<128, 16, 2><<<dim3(64, 2, 2), blk, 0, stream>>>(y3, w_t4, t4H, 32);
  // t5: conv3x3 -> NCHW f32 final                [single-f16]
  conv3x3_mfma_k<32, 32, 32, 0, 0, 1><<<dim3(512), blk, 0, stream>>>(
      t4H, t4H, t4H, t4H, 32, t5H_w, t5L_w, nullptr, out, nullptr, nullptr);
}

// Round 16
// 646.712 us; speedup vs baseline: 1.3309x; 1.0710x over previous
//
#include <hip/hip_runtime.h>
#include <math.h>

static constexpr int H = 256, W = 256, HW = H * W;

typedef __attribute__((ext_vector_type(8))) _Float16 half8v;  // 16B
typedef __attribute__((ext_vector_type(4))) _Float16 half4v;  // 8B
typedef __attribute__((ext_vector_type(4))) float  float4v;   // MFMA acc

__device__ __forceinline__ half8v h8zero() {
  half8v z;
  #pragma unroll
  for (int i = 0; i < 8; ++i) z[i] = (_Float16)0;
  return z;
}

// ---------- activations ----------
__device__ __forceinline__ float gelu_f(float v) {
  return 0.5f * v * (1.0f + erff(v * 0.70710678118654752440f));
}
template<int ACT>
__device__ __forceinline__ float apply_act(float v) {
  if constexpr (ACT == 1) return v >= 0.f ? v : 0.1f * v;   // LeakyReLU(0.1)
  if constexpr (ACT == 2) return gelu_f(v);
  return v;
}

// ---------- pack both inputs: NCHW f32 (C=32) -> chunked NHWC f16 hi + scaled lo ----------
__global__ __launch_bounds__(256)
void pack2_k(const float* __restrict__ inA, _Float16* __restrict__ hiA, _Float16* __restrict__ loA,
             const float* __restrict__ inB, _Float16* __restrict__ hiB, _Float16* __restrict__ loB)
{
  const int p = blockIdx.x * 256 + threadIdx.x;
  const int b = blockIdx.y;
  const float* in = blockIdx.z ? inB : inA;
  _Float16* hi = blockIdx.z ? hiB : hiA;
  _Float16* lo = blockIdx.z ? loB : loA;
  const float* ip = in + (size_t)b * 32 * HW + p;
  __attribute__((aligned(16))) _Float16 hv[32], lv[32];
  #pragma unroll
  for (int c = 0; c < 32; ++c) {
    float v = ip[(size_t)c * HW];
    _Float16 h = (_Float16)v;
    hv[c] = h;
    lv[c] = (_Float16)((v - (float)h) * 2048.0f);
  }
  size_t ob = ((size_t)b * HW + p) * 32;
  #pragma unroll
  for (int j = 0; j < 4; ++j) {
    *(half8v*)&hi[ob + j * 8] = *(half8v*)&hv[j * 8];
    *(half8v*)&lo[ob + j * 8] = *(half8v*)&lv[j * 8];
  }
}

// ---------- weight prep x3: [OC][CIN][3][3] f32 -> [tap][OC][CIN] f16 hi + scaled lo ----------
__device__ __forceinline__ void prep_w_body(const float* w, _Float16* hi, _Float16* lo,
                                            int OC, int CIN, int tid)
{
  if (tid >= OC * CIN * 9) return;
  int ci = tid % CIN; int r = tid / CIN; int oc = r % OC; int tap = r / OC;
  float v = w[((size_t)oc * CIN + ci) * 9 + tap];
  _Float16 h = (_Float16)v;
  hi[tid] = h;
  lo[tid] = (_Float16)((v - (float)h) * 2048.0f);
}
__global__ __launch_bounds__(256)
void prep3_w_k(const float* __restrict__ w0, _Float16* __restrict__ h0, _Float16* __restrict__ l0, int OC0, int CIN0, int nb0,
               const float* __restrict__ w1, _Float16* __restrict__ h1, _Float16* __restrict__ l1, int OC1, int CIN1, int nb1,
               const float* __restrict__ w2, _Float16* __restrict__ h2, _Float16* __restrict__ l2, int OC2, int CIN2)
{
  int bb = blockIdx.x;
  if (bb < nb0)            prep_w_body(w0, h0, l0, OC0, CIN0, bb * 256 + threadIdx.x);
  else if (bb < nb0 + nb1) prep_w_body(w1, h1, l1, OC1, CIN1, (bb - nb0) * 256 + threadIdx.x);
  else                     prep_w_body(w2, h2, l2, OC2, CIN2, (bb - nb0 - nb1) * 256 + threadIdx.x);
}

// ---------- 3x3 conv, f16 MFMA; r15-proven structure + setprio(T5) ----------
// Full LDS staging (hi+lo for SPLIT=3), 64-px F=4 wave tile, per-tap weight
// loads from global (L2-hot). OCB=32 for dcn (r15: 242 us best).
// SPLIT=3: split-3 (accP + accQ/2048) — pre-top-k. SPLIT=1: hi only — tail.
// OMODE: 0 = NCHW f32 out, 1 = NHWC f16 hi/lo out, 3 = NHWC f16 hi only.
// 1-D grid, bijective XCD-grouped decode (r9: dcn FETCH 144->36 MB).
// MFMA 16x16x32 f16 (HW-verified r5-r15): A row=l&15 (oc), k=(l>>4)*8+j;
//   B col=l&15 (px); D col=l&15 (px), row=(l>>4)*4+reg (oc).
template<int CIN, int OC, int OCB, int ACT, int OMODE, int SPLIT>
__global__ __launch_bounds__(256)
void conv3x3_mfma_k(const _Float16* __restrict__ iH0, const _Float16* __restrict__ iL0,
                    const _Float16* __restrict__ iH1, const _Float16* __restrict__ iL1, int cin0,
                    const _Float16* __restrict__ wHi, const _Float16* __restrict__ wLo,
                    const float* __restrict__ bias,
                    float* __restrict__ outF, _Float16* __restrict__ oH, _Float16* __restrict__ oL)
{
  constexpr int NOF  = OCB / 16;
  constexpr int NAQ  = (SPLIT == 3) ? NOF : 1;
  constexpr int REC  = (SPLIT == 3) ? 64 : 32;
  constexpr int nOcg = OC / OCB;
  __shared__ _Float16 sB[6 * 66 * REC];

  const int l  = threadIdx.x & 63;
  const int wv = threadIdx.x >> 6;

  const int bid = blockIdx.x;
  const int xcd = bid & 7, q = bid >> 3;
  const int ocg  = q % nOcg;
  const int tIdx = (q / nOcg) * 8 + xcd;
  const int b   = tIdx >> 8;
  const int x0  = ((tIdx >> 6) & 3) * 64;
  const int y0  = (tIdx & 63) * 4;
  const int oc0 = ocg * OCB;

  float4v accP[NOF][4];
  float4v accQ[NAQ][4];
  #pragma unroll
  for (int j = 0; j < NOF; ++j)
    #pragma unroll
    for (int f = 0; f < 4; ++f)
      accP[j][f] = (float4v){0.f, 0.f, 0.f, 0.f};
  #pragma unroll
  for (int j = 0; j < NAQ; ++j)
    #pragma unroll
    for (int f = 0; f < 4; ++f)
      accQ[j][f] = (float4v){0.f, 0.f, 0.f, 0.f};

  const int k8  = (l >> 4) * 8;
  const int ocl = l & 15;
  const int rowy = y0 + wv;
  const int sq  = l & 3;          // ci granule (staging)
  const int spx = l >> 2;         // px offset within 16-px subtile (staging)

  #pragma unroll 1
  for (int cc = 0; cc < CIN; cc += 32) {
    const _Float16 *cbH, *cbL;
    if (cc < cin0) {
      size_t o = (size_t)(b * (cin0 >> 5) + (cc >> 5)) * HW * 32;
      cbH = iH0 + o; cbL = iL0 + o;
    } else {
      size_t o = (size_t)(b * ((CIN - cin0) >> 5) + ((cc - cin0) >> 5)) * HW * 32;
      cbH = iH1 + o; cbL = iL1 + o;
    }
    __syncthreads();
    if constexpr (SPLIT == 3) {
      // 60 wave-tasks = 6 rows x {hi,lo} x 5 px-subtiles
      #pragma unroll 2
      for (int t = wv; t < 60; t += 4) {
        int r = t / 10; int rem = t - r * 10; int bsel = rem / 5; int s = rem - bsel * 5;
        const _Float16* src = bsel ? cbL : cbH;
        int gy = y0 + r - 1;
        bool vy = (gy >= 0) && (gy < H);
        int gyc = gy < 0 ? 0 : (gy >= H ? H - 1 : gy);
        int pxl = s * 16 + spx;
        bool lact = (s < 4) || (l < 8);
        int gx = x0 + pxl - 1;
        bool vx = (gx >= 0) && (gx < W);
        int gxc = gx < 0 ? 0 : (gx >= W ? W - 1 : gx);
        half8v v = h8zero();
        if (lact && vy && vx)
          v = *(const half8v*)&src[((size_t)gyc * W + gxc) * 32 + sq * 8];
        int cls = (sq + (bsel ? 4 : 0)) ^ (pxl & 7);
        if (lact)
          *(half8v*)&sB[(r * 66 + pxl) * 64 + cls * 8] = v;
      }
    } else {
      // 30 wave-tasks = 6 rows x 5 px-subtiles (hi only)
      #pragma unroll 2
      for (int t = wv; t < 30; t += 4) {
        int r = t / 5; int s = t - r * 5;
        int gy = y0 + r - 1;
        bool vy = (gy >= 0) && (gy < H);
        int gyc = gy < 0 ? 0 : (gy >= H ? H - 1 : gy);
        int pxl = s * 16 + spx;
        bool lact = (s < 4) || (l < 8);
        int gx = x0 + pxl - 1;
        bool vx = (gx >= 0) && (gx < W);
        int gxc = gx < 0 ? 0 : (gx >= W ? W - 1 : gx);
        half8v v = h8zero();
        if (lact && vy && vx)
          v = *(const half8v*)&cbH[((size_t)gyc * W + gxc) * 32 + sq * 8];
        int cls = (sq ^ pxl) & 3;
        if (lact)
          *(half8v*)&sB[(r * 66 + pxl) * 32 + cls * 8] = v;
      }
    }
    __syncthreads();

    #pragma unroll 1
    for (int tap = 0; tap < 9; ++tap) {
      const int dy = tap / 3, dx = tap - 3 * (tap / 3);
      half8v ah[NOF], aq[NAQ];
      const _Float16* hp = wHi + ((size_t)tap * OC + oc0 + ocl) * CIN + cc + k8;
      #pragma unroll
      for (int j = 0; j < NOF; ++j)
        ah[j] = *(const half8v*)(hp + (size_t)j * 16 * CIN);
      if constexpr (SPLIT == 3) {
        const _Float16* lp = wLo + ((size_t)tap * OC + oc0 + ocl) * CIN + cc + k8;
        #pragma unroll
        for (int j = 0; j < NOF; ++j)
          aq[j] = *(const half8v*)(lp + (size_t)j * 16 * CIN);
      }
      const int px = ocl + dx;
      if constexpr (SPLIT == 3) {
        const int rbase = ((wv + dy) * 66 + px) * 64;
        const int clsH = (l >> 4) ^ (px & 7);
        const int clsQ = ((l >> 4) + 4) ^ (px & 7);
        __builtin_amdgcn_s_setprio(1);
        #pragma unroll
        for (int f = 0; f < 4; ++f) {
          half8v bh = *(const half8v*)&sB[rbase + f * 1024 + clsH * 8];
          half8v bq = *(const half8v*)&sB[rbase + f * 1024 + clsQ * 8];
          #pragma unroll
          for (int j = 0; j < NOF; ++j) {
            accP[j][f] = __builtin_amdgcn_mfma_f32_16x16x32_f16(ah[j], bh, accP[j][f], 0, 0, 0);
            accQ[j][f] = __builtin_amdgcn_mfma_f32_16x16x32_f16(ah[j], bq, accQ[j][f], 0, 0, 0);
            accQ[j][f] = __builtin_amdgcn_mfma_f32_16x16x32_f16(aq[j], bh, accQ[j][f], 0, 0, 0);
          }
        }
        __builtin_amdgcn_s_setprio(0);
      } else {
        const int rbase = ((wv + dy) * 66 + px) * 32;
        const int clsH = ((l >> 4) ^ px) & 3;
        __builtin_amdgcn_s_setprio(1);
        #pragma unroll
        for (int f = 0; f < 4; ++f) {
          half8v bh = *(const half8v*)&sB[rbase + f * 512 + clsH * 8];
          #pragma unroll
          for (int j = 0; j < NOF; ++j)
            accP[j][f] = __builtin_amdgcn_mfma_f32_16x16x32_f16(ah[j], bh, accP[j][f], 0, 0, 0);
        }
        __builtin_amdgcn_s_setprio(0);
      }
    }
  }

  // ---- epilogue: D col=l&15 (px), row=(l>>4)*4+reg (oc) ----
  #pragma unroll
  for (int j = 0; j < NOF; ++j)
    #pragma unroll
    for (int f = 0; f < 4; ++f) {
      const int px  = x0 + f * 16 + ocl;
      const int occ = oc0 + j * 16 + (l >> 4) * 4;
      float vv4[4];
      #pragma unroll
      for (int r = 0; r < 4; ++r) {
        float bv = bias ? bias[occ + r] : 0.f;
        float vv = accP[j][f][r] + bv;
        if constexpr (SPLIT == 3) vv += accQ[j][f][r] * (1.0f / 2048.0f);
        vv4[r] = apply_act<ACT>(vv);
      }
      if constexpr (OMODE == 0) {
        #pragma unroll
        for (int r = 0; r < 4; ++r)
          outF[((size_t)(b * OC + occ + r) * H + rowy) * W + px] = vv4[r];
      } else if constexpr (OMODE == 1) {
        __attribute__((aligned(8))) _Float16 hv[4], lv[4];
        #pragma unroll
        for (int r = 0; r < 4; ++r) {
          _Float16 h = (_Float16)vv4[r];
          hv[r] = h;
          lv[r] = (_Float16)((vv4[r] - (float)h) * 2048.0f);
        }
        size_t ob = ((size_t)b * HW + (size_t)rowy * W + px) * OC + occ;
        *(half4v*)&oH[ob] = *(half4v*)&hv[0];
        *(half4v*)&oL[ob] = *(half4v*)&lv[0];
      } else {
        // OMODE == 3: NHWC f16 hi only
        __attribute__((aligned(8))) _Float16 hv[4];
        #pragma unroll
        for (int r = 0; r < 4; ++r) hv[r] = (_Float16)vv4[r];
        size_t ob = ((size_t)b * HW + (size_t)rowy * W + px) * OC + occ;
        *(half4v*)&oH[ob] = *(half4v*)&hv[0];
      }
    }
}

// ---------- 1x1 conv: NHWC f16 in -> chunked NHWC f16 out (hi only) ----------
template<int CIN, int OCB, int ACT>
__global__ __launch_bounds__(256)
void conv1x1_nhwc_k(const _Float16* __restrict__ in, const float* __restrict__ w,
                    _Float16* __restrict__ oH, int OC)
{
  __shared__ __align__(16) float sW[OCB][CIN];
  const int b   = blockIdx.y;
  const int oc0 = blockIdx.z * OCB;
  for (int t = threadIdx.x; t < OCB * CIN; t += 256)
    sW[t / CIN][t % CIN] = w[(size_t)(oc0 + t / CIN) * CIN + (t % CIN)];
  __syncthreads();

  const int pb = blockIdx.x * 1024 + threadIdx.x;    // 4 px at stride 256
  float acc[OCB][4];
  #pragma unroll
  for (int o = 0; o < OCB; ++o)
    #pragma unroll
    for (int i = 0; i < 4; ++i) acc[o][i] = 0.f;

  #pragma unroll 1
  for (int c0 = 0; c0 < CIN; c0 += 8) {
    float v[4][8];
    #pragma unroll
    for (int i = 0; i < 4; ++i) {
      const _Float16* ip = in + ((size_t)b * HW + pb + i * 256) * CIN + c0;
      half8v hv8 = *(const half8v*)ip;
      #pragma unroll
      for (int j = 0; j < 8; ++j) v[i][j] = (float)hv8[j];
    }
    #pragma unroll
    for (int o = 0; o < OCB; ++o) {
      const float4 w0 = *(const float4*)&sW[o][c0];
      const float4 w1 = *(const float4*)&sW[o][c0 + 4];
      #pragma unroll
      for (int i = 0; i < 4; ++i) {
        acc[o][i] += v[i][0]*w0.x + v[i][1]*w0.y + v[i][2]*w0.z + v[i][3]*w0.w
                   + v[i][4]*w1.x + v[i][5]*w1.y + v[i][6]*w1.z + v[i][7]*w1.w;
      }
    }
  }
  #pragma unroll
  for (int i = 0; i < 4; ++i) {
    __attribute__((aligned(16))) _Float16 hv[OCB];
    #pragma unroll
    for (int o = 0; o < OCB; ++o)
      hv[o] = (_Float16)apply_act<ACT>(acc[o][i]);
    size_t ob = ((size_t)(b * (OC >> 5) + (oc0 >> 5)) * HW + pb + i * 256) * 32 + (oc0 & 31);
    #pragma unroll
    for (int j = 0; j < OCB / 8; ++j)
      *(half8v*)&oH[ob + j * 8] = *(half8v*)&hv[j * 8];
  }
}

// ---------- corr + top-3, 2 px/thread float2 (jax tie-break: lower index wins) ----------
// grid (HW/512, B) = 256 blocks -> full-device coverage (r15's 128 left half idle).
__global__ __launch_bounds__(256)
void corr_topk_k(const float* __restrict__ warp, const float* __restrict__ x,
                 int* __restrict__ idxo)
{
  const int p2 = (blockIdx.x * 256 + threadIdx.x) * 2;
  const int b = blockIdx.y;
  float corr[9][2];
  #pragma unroll
  for (int o = 0; o < 9; ++o) { corr[o][0] = 0.f; corr[o][1] = 0.f; }
  #pragma unroll 1
  for (int c = 0; c < 32; ++c) {
    float2 xv = *(const float2*)&x[((size_t)b * 32 + c) * HW + p2];
    const float* wp = warp + ((size_t)b * 288 + (size_t)c * 9) * HW + p2;
    #pragma unroll
    for (int o = 0; o < 9; ++o) {
      float2 wv = *(const float2*)&wp[(size_t)o * HW];
      corr[o][0] += wv.x * xv.x;
      corr[o][1] += wv.y * xv.y;
    }
  }
  int2 packs;
  #pragma unroll
  for (int i = 0; i < 2; ++i) {
    unsigned mask = 0;
    int packed = 0;
    #pragma unroll
    for (int t = 0; t < 3; ++t) {
      float best = -INFINITY; int bi = 0;
      #pragma unroll
      for (int o = 0; o < 9; ++o) {
        bool take = (((mask >> o) & 1u) == 0u) && (corr[o][i] > best);
        best = take ? corr[o][i] : best;
        bi   = take ? o          : bi;
      }
      mask   |= 1u << bi;
      packed |= bi << (4 * t);
    }
    ((int*)&packs)[i] = packed;
  }
  *(int2*)&idxo[(size_t)b * HW + p2] = packs;
}

// ---------- gather selected warps + 3x3 conv with w_sel; out 32-ch NHWC f16 (hi only) ----------
__global__ __launch_bounds__(256)
void selconv_k(const float* __restrict__ warp, const int* __restrict__ idxp,
               const float* __restrict__ wsel, const float* __restrict__ bsel,
               _Float16* __restrict__ oH)
{
  const int tx = threadIdx.x & 31, ty = threadIdx.x >> 5;
  const int px = blockIdx.x * 32 + tx;
  const int py = blockIdx.y * 8 + ty;
  const int b  = blockIdx.z;

  int  nidx[9];
  bool nval[9];
  int  qoff[9];
  #pragma unroll
  for (int kh = 0; kh < 3; ++kh)
    #pragma unroll
    for (int kw = 0; kw < 3; ++kw) {
      int k = kh * 3 + kw;
      int qy = py + kh - 1, qx = px + kw - 1;
      nval[k] = (qy >= 0 && qy < H && qx >= 0 && qx < W);
      qoff[k] = qy * W + qx;
      nidx[k] = nval[k] ? idxp[(size_t)b * HW + qoff[k]] : 0;
    }

  float ws27[27];
  #pragma unroll
  for (int i = 0; i < 27; ++i) ws27[i] = wsel[i];
  const float bs = bsel[0];

  float arr[32];
  #pragma unroll 1
  for (int c = 0; c < 32; ++c) {
    float acc = bs;
    const float* wb = warp + ((size_t)b * 288 + (size_t)c * 9) * HW;
    #pragma unroll
    for (int k = 0; k < 9; ++k) {
      if (nval[k]) {
        int pk = nidx[k];
        #pragma unroll
        for (int t = 0; t < 3; ++t) {
          int o = (pk >> (4 * t)) & 15;
          acc += ws27[t * 9 + k] * wb[(size_t)o * HW + qoff[k]];
        }
      }
    }
    arr[c] = acc;
  }

  __attribute__((aligned(16))) _Float16 hv[32];
  #pragma unroll
  for (int c = 0; c < 32; ++c) hv[c] = (_Float16)arr[c];
  size_t ob = ((size_t)b * HW + (size_t)py * W + px) * 32;
  #pragma unroll
  for (int j = 0; j < 4; ++j)
    *(half8v*)&oH[ob + j * 8] = *(half8v*)&hv[j * 8];
}

// ---------- launch ----------
extern "C" void kernel_launch(void* const* d_in, const int* in_sizes, int n_in,
                              void* d_out, int out_size, void* d_ws, size_t ws_size,
                              hipStream_t stream) {
  const float* x      = (const float*)d_in[0];
  const float* key    = (const float*)d_in[1];
  const float* w_off1 = (const float*)d_in[2];
  const float* b_off1 = (const float*)d_in[3];
  const float* w_off2 = (const float*)d_in[4];
  const float* b_off2 = (const float*)d_in[5];
  const float* w_dcn  = (const float*)d_in[6];
  const float* b_dcn  = (const float*)d_in[7];
  const float* w_sel  = (const float*)d_in[8];
  const float* b_sel  = (const float*)d_in[9];
  const float* w_t1   = (const float*)d_in[10];
  const float* w_t2   = (const float*)d_in[11];
  const float* w_t3   = (const float*)d_in[12];
  const float* w_t4   = (const float*)d_in[13];
  const float* w_t5   = (const float*)d_in[14];

  // ---- workspace layout (peak ~185.2 MB; proven safe r5-r15) ----
  char* ws = (char*)d_ws;
  float* warp = (float*)(ws);                                // [2,288,HW] f32 NCHW, 144 MiB
  // pre-dcn scratch inside warp region (dead before dcn writes):
  _Float16* xH  = (_Float16*)(ws);                           // 8 MiB
  _Float16* xL  = (_Float16*)(ws + 8388608);
  _Float16* o1H = (_Float16*)(ws + 16777216);                // off1 out, 8+8 MiB
  _Float16* o1L = (_Float16*)(ws + 25165824);
  _Float16* w1H = (_Float16*)(ws + 33554432);                // off1/off2 weight tables
  _Float16* w1L = w1H + 18432;
  _Float16* w2H = w1L + 18432;
  _Float16* w2L = w2H + 9216;
  // outside warp region:
  _Float16* kH  = (_Float16*)(ws + 150994944);               // key pack, 8+8 MiB
  _Float16* kL  = (_Float16*)(ws + 159383552);
  _Float16* o2H = (_Float16*)(ws + 167772160);               // off2 out, 8+8 MiB
  _Float16* o2L = (_Float16*)(ws + 176160768);
  _Float16* wdH = (_Float16*)(ws + 184549376);               // dcn tables (165888 each)
  _Float16* wdL = wdH + 165888;                              // ends ~185.2 MB
  // post-dcn:
  int*      idxb = (int*)(ws + 150994944);                   // 0.5 MiB (over kH, dead)
  _Float16* kwH  = (_Float16*)(ws + 159383552);              // selconv out hi (over kL)
  _Float16* twB  = (_Float16*)(ws + 176160768);              // tail tables (over o2L)
  _Float16* t1H_w = twB;
  _Float16* t1L_w = twB + 9216;
  _Float16* t3H_w = twB + 18432;
  _Float16* t3L_w = twB + 165888;
  _Float16* t5H_w = twB + 313344;
  _Float16* t5L_w = twB + 322560;
  // tail activations inside dead warp region (all f16 now):
  _Float16* y1  = (_Float16*)(ws);                           // t1 out NHWC f16 [2,HW,32], 8 MiB
  _Float16* t2H = (_Float16*)(ws + 16777216);                // chunked [2,4,HW,32] f16, 32 MiB
  _Float16* y3  = (_Float16*)(ws + 83886080);                // t3 out NHWC f16 [2,HW,128], 32 MiB
  _Float16* t4H = (_Float16*)(ws + 50331648);                // 8 MiB
  float* out = (float*)d_out;

  dim3 blk(256);

  // pack x,key -> chunked f16 hi/lo (one launch)
  pack2_k<<<dim3(256, 2, 2), blk, 0, stream>>>(x, xH, xL, key, kH, kL);
  // phase-1 weight tables (one launch: off1 72 blk, off2 36 blk, dcn 648 blk)
  prep3_w_k<<<dim3(756), blk, 0, stream>>>(
      w_off1, w1H, w1L, 32, 64, 72,
      w_off2, w2H, w2L, 32, 32, 36,
      w_dcn,  wdH, wdL, 288, 64);

  // off1 = lrelu(conv(concat(x,key)))  -> f16 hi/lo   [split-3, pre-topk]
  conv3x3_mfma_k<64, 32, 32, 1, 1, 3><<<dim3(512), blk, 0, stream>>>(
      xH, xL, kH, kL, 32, w1H, w1L, b_off1, nullptr, o1H, o1L);
  // off2 = lrelu(conv(off1))           -> f16 hi/lo   [split-3]
  conv3x3_mfma_k<32, 32, 32, 1, 1, 3><<<dim3(512), blk, 0, stream>>>(
      o1H, o1L, o1H, o1L, 32, w2H, w2L, b_off2, nullptr, o2H, o2L);
  // warp = conv(concat(key,off2))      -> NCHW f32    [split-3, OCB=32]
  conv3x3_mfma_k<64, 288, 32, 0, 0, 3><<<dim3(4608), blk, 0, stream>>>(
      kH, kL, o2H, o2L, 32, wdH, wdL, b_dcn, warp, nullptr, nullptr);
  // corr + top-3 (2 px/thread float2, 256 blocks)
  corr_topk_k<<<dim3(128, 2), blk, 0, stream>>>(warp, x, idxb);
  // key_warp -> f16 hi (tail is single-f16; lo unused)
  selconv_k<<<dim3(8, 32, 2), blk, 0, stream>>>(warp, idxb, w_sel, b_sel, kwH);

  // phase-2 weight tables (one launch: t1 36, t3 576, t5 36)
  prep3_w_k<<<dim3(648), blk, 0, stream>>>(
      w_t1, t1H_w, t1L_w, 32, 32, 36,
      w_t3, t3H_w, t3L_w, 128, 128, 576,
      w_t5, t5H_w, t5L_w, 32, 32);

  // t1: conv3x3 (gelu) -> NHWC f16 y1            [single-f16]
  conv3x3_mfma_k<32, 32, 32, 2, 3, 1><<<dim3(512), blk, 0, stream>>>(
      kwH, kwH, kwH, kwH, 32, t1H_w, t1L_w, nullptr, nullptr, y1, nullptr);
  // t2: 1x1 (gelu) -> chunked f16 hi [2,4,HW,32]
  conv1x1_nhwc_k<32, 16, 2><<<dim3(64, 2, 8), blk, 0, stream>>>(y1, w_t2, t2H, 128);
  // t3: conv3x3 (gelu) -> NHWC f16 y3            [single-f16, OCB=64]
  conv3x3_mfma_k<128, 128, 64, 2, 3, 1><<<dim3(1024), blk, 0, stream>>>(
      t2H, t2H, t2H, t2H, 128, t3H_w, t3L_w, nullptr, nullptr, y3, nullptr);
  // t4: 1x1 (gelu) -> f16 hi
  conv1x1_nhwc_k<128, 16, 2><<<dim3(64, 2, 2), blk, 0, stream>>>(y3, w_t4, t4H, 32);
  // t5: conv3x3 -> NCHW f32 final                [single-f16]
  conv3x3_mfma_k<32, 32, 32, 0, 0, 1><<<dim3(512), blk, 0, stream>>>(
      t4H, t4H, t4H, t4H, 32, t5H_w, t5L_w, nullptr, out, nullptr, nullptr);
}

// Round 17
// 605.986 us; speedup vs baseline: 1.4203x; 1.0672x over previous
//
#include <hip/hip_runtime.h>
#include <math.h>

static constexpr int H = 256, W = 256, HW = H * W;
static constexpr int PW = 258, PREC = 66564;   // padded width, padded px/batch (258*258)

typedef __attribute__((ext_vector_type(8))) _Float16 half8v;  // 16B
typedef __attribute__((ext_vector_type(4))) _Float16 half4v;  // 8B
typedef __attribute__((ext_vector_type(4))) float  float4v;   // MFMA acc

__device__ __forceinline__ half8v h8zero() {
  half8v z;
  #pragma unroll
  for (int i = 0; i < 8; ++i) z[i] = (_Float16)0;
  return z;
}

// global_load_lds: per-lane global src (16B), wave-uniform LDS base; lane i -> base + i*16.
__device__ __forceinline__ void gload_lds16(const _Float16* g, _Float16* lds) {
  __builtin_amdgcn_global_load_lds(
      (const __attribute__((address_space(1))) void*)g,
      (__attribute__((address_space(3))) void*)lds, 16, 0, 0);
}

// ---------- activations ----------
__device__ __forceinline__ float gelu_f(float v) {
  return 0.5f * v * (1.0f + erff(v * 0.70710678118654752440f));
}
template<int ACT>
__device__ __forceinline__ float apply_act(float v) {
  if constexpr (ACT == 1) return v >= 0.f ? v : 0.1f * v;   // LeakyReLU(0.1)
  if constexpr (ACT == 2) return gelu_f(v);
  return v;
}

// ---------- zero the 1-px borders of 4 packed-padded buffers (x2 batches) ----------
__global__ __launch_bounds__(256)
void zero_border_k(_Float16* p0, _Float16* p1, _Float16* p2, _Float16* p3)
{
  int t = blockIdx.x * 256 + threadIdx.x;
  if (t >= 1028) return;
  int inst = blockIdx.y;                 // 0..7
  _Float16* P = (inst >> 1) == 0 ? p0 : ((inst >> 1) == 1 ? p1 : ((inst >> 1) == 2 ? p2 : p3));
  int b = inst & 1;
  int y, x;
  if      (t < 258) { y = 0;          x = t; }
  else if (t < 516) { y = 257;        x = t - 258; }
  else if (t < 772) { y = t - 515;    x = 0; }       // rows 1..256
  else              { y = t - 771;    x = 257; }
  _Float16* o = P + (((size_t)b * PW + y) * PW + x) * 64;
  half8v z = h8zero();
  #pragma unroll
  for (int j = 0; j < 8; ++j) *(half8v*)&o[j * 8] = z;
}

// ---------- pack x,key: NCHW f32 -> packed-padded [B][258][258][64]: hi(0..31)+lo(32..63) ----------
__global__ __launch_bounds__(256)
void pack2_k(const float* __restrict__ inA, _Float16* __restrict__ pA,
             const float* __restrict__ inB, _Float16* __restrict__ pB)
{
  const int p = blockIdx.x * 256 + threadIdx.x;
  const int b = blockIdx.y;
  const float* in = blockIdx.z ? inB : inA;
  _Float16* P = blockIdx.z ? pB : pA;
  const float* ip = in + (size_t)b * 32 * HW + p;
  __attribute__((aligned(16))) _Float16 hv[32], lv[32];
  #pragma unroll
  for (int c = 0; c < 32; ++c) {
    float v = ip[(size_t)c * HW];
    _Float16 h = (_Float16)v;
    hv[c] = h;
    lv[c] = (_Float16)((v - (float)h) * 2048.0f);
  }
  const int y = p >> 8, xcol = p & 255;
  _Float16* o = P + (((size_t)b * PW + y + 1) * PW + xcol + 1) * 64;
  #pragma unroll
  for (int j = 0; j < 4; ++j) {
    *(half8v*)&o[j * 8]      = *(half8v*)&hv[j * 8];
    *(half8v*)&o[32 + j * 8] = *(half8v*)&lv[j * 8];
  }
}

// ---------- weight prep x3: [OC][CIN][3][3] f32 -> [tap][OC][CIN] f16 hi + scaled lo ----------
__device__ __forceinline__ void prep_w_body(const float* w, _Float16* hi, _Float16* lo,
                                            int OC, int CIN, int tid)
{
  if (tid >= OC * CIN * 9) return;
  int ci = tid % CIN; int r = tid / CIN; int oc = r % OC; int tap = r / OC;
  float v = w[((size_t)oc * CIN + ci) * 9 + tap];
  _Float16 h = (_Float16)v;
  hi[tid] = h;
  lo[tid] = (_Float16)((v - (float)h) * 2048.0f);
}
__global__ __launch_bounds__(256)
void prep3_w_k(const float* __restrict__ w0, _Float16* __restrict__ h0, _Float16* __restrict__ l0, int OC0, int CIN0, int nb0,
               const float* __restrict__ w1, _Float16* __restrict__ h1, _Float16* __restrict__ l1, int OC1, int CIN1, int nb1,
               const float* __restrict__ w2, _Float16* __restrict__ h2, _Float16* __restrict__ l2, int OC2, int CIN2)
{
  int bb = blockIdx.x;
  if (bb < nb0)            prep_w_body(w0, h0, l0, OC0, CIN0, bb * 256 + threadIdx.x);
  else if (bb < nb0 + nb1) prep_w_body(w1, h1, l1, OC1, CIN1, (bb - nb0) * 256 + threadIdx.x);
  else                     prep_w_body(w2, h2, l2, OC2, CIN2, (bb - nb0 - nb1) * 256 + threadIdx.x);
}

// ---------- 3x3 conv, f16 MFMA ----------
// SPLIT=3 (pre-topk): inputs are PACKED-PADDED [B][258][258][64] (hi+lo);
//   staging via global_load_lds (1KB/instr, linear LDS dest) with PRE-SWIZZLED
//   global source m=(l&7)^(l>>3) -> staged bytes identical to r16's verified
//   XOR layout; read path unchanged. Edge px 64-65 staged via 16-lane ds_write.
// SPLIT=1 (tail): r16 VGPR staging from chunked hi-only tensors, unchanged.
// OMODE: 0 = NCHW f32 out, 1 = packed-padded hi/lo out, 3 = NHWC f16 hi only.
// MFMA 16x16x32 f16 (HW-verified r5-r16): A row=l&15 (oc), k=(l>>4)*8+j;
//   B col=l&15 (px); D col=l&15 (px), row=(l>>4)*4+reg (oc).
template<int CIN, int OC, int OCB, int ACT, int OMODE, int SPLIT>
__global__ __launch_bounds__(256)
void conv3x3_mfma_k(const _Float16* __restrict__ iH0, const _Float16* __restrict__ iL0,
                    const _Float16* __restrict__ iH1, const _Float16* __restrict__ iL1, int cin0,
                    const _Float16* __restrict__ wHi, const _Float16* __restrict__ wLo,
                    const float* __restrict__ bias,
                    float* __restrict__ outF, _Float16* __restrict__ oH, _Float16* __restrict__ oL)
{
  constexpr int NOF  = OCB / 16;
  constexpr int NAQ  = (SPLIT == 3) ? NOF : 1;
  constexpr int REC  = (SPLIT == 3) ? 64 : 32;
  constexpr int nOcg = OC / OCB;
  __shared__ _Float16 sB[6 * 66 * REC];

  const int l  = threadIdx.x & 63;
  const int wv = threadIdx.x >> 6;

  const int bid = blockIdx.x;
  const int xcd = bid & 7, q = bid >> 3;
  const int ocg  = q % nOcg;
  const int tIdx = (q / nOcg) * 8 + xcd;
  const int b   = tIdx >> 8;
  const int x0  = ((tIdx >> 6) & 3) * 64;
  const int y0  = (tIdx & 63) * 4;
  const int oc0 = ocg * OCB;

  float4v accP[NOF][4];
  float4v accQ[NAQ][4];
  #pragma unroll
  for (int j = 0; j < NOF; ++j)
    #pragma unroll
    for (int f = 0; f < 4; ++f)
      accP[j][f] = (float4v){0.f, 0.f, 0.f, 0.f};
  #pragma unroll
  for (int j = 0; j < NAQ; ++j)
    #pragma unroll
    for (int f = 0; f < 4; ++f)
      accQ[j][f] = (float4v){0.f, 0.f, 0.f, 0.f};

  const int k8  = (l >> 4) * 8;
  const int ocl = l & 15;
  const int rowy = y0 + wv;
  const int sq  = l & 3;          // ci granule (SPLIT=1 staging)
  const int spx = l >> 2;         // px offset (SPLIT=1 staging)

  #pragma unroll 1
  for (int cc = 0; cc < CIN; cc += 32) {
    if constexpr (SPLIT == 3) {
      const _Float16* cb = (cc < cin0 ? iH0 : iH1) + (size_t)b * ((size_t)PREC * 64);
      __syncthreads();
      // ---- 48 gll tasks: 6 rows x 8 px-groups; 12 per wave ----
      #pragma unroll
      for (int k = 0; k < 12; ++k) {
        int t = wv + 4 * k;                 // wave-uniform
        int r = t >> 3, s = t & 7;
        const _Float16* src = cb
            + (((size_t)(y0 + r) * PW) + (x0 + s * 8 + (l >> 3))) * 64
            + ((l & 7) ^ (l >> 3)) * 8;     // pre-swizzled granule
        gload_lds16(src, &sB[(r * 66 + s * 8) * 64]);
      }
      // ---- edge px 64,65: 16-lane VGPR copies ----
      #pragma unroll
      for (int rr = wv; rr < 6; rr += 4) {
        if (l < 16) {
          int pxo = l >> 3;                 // 0,1
          int slot = l & 7;
          const _Float16* src = cb
              + (((size_t)(y0 + rr) * PW) + (x0 + 64 + pxo)) * 64 + (slot ^ pxo) * 8;
          half8v v = *(const half8v*)src;
          *(half8v*)&sB[(rr * 66 + 64 + pxo) * 64 + slot * 8] = v;
        }
      }
      __syncthreads();
    } else {
      const _Float16* cbH;
      {
        size_t o = (size_t)(b * (CIN >> 5) + (cc >> 5)) * HW * 32;
        cbH = iH0 + o;
      }
      __syncthreads();
      // 30 wave-tasks = 6 rows x 5 px-subtiles (hi only)
      #pragma unroll 2
      for (int t = wv; t < 30; t += 4) {
        int r = t / 5; int s = t - r * 5;
        int gy = y0 + r - 1;
        bool vy = (gy >= 0) && (gy < H);
        int gyc = gy < 0 ? 0 : (gy >= H ? H - 1 : gy);
        int pxl = s * 16 + spx;
        bool lact = (s < 4) || (l < 8);
        int gx = x0 + pxl - 1;
        bool vx = (gx >= 0) && (gx < W);
        int gxc = gx < 0 ? 0 : (gx >= W ? W - 1 : gx);
        half8v v = h8zero();
        if (lact && vy && vx)
          v = *(const half8v*)&cbH[((size_t)gyc * W + gxc) * 32 + sq * 8];
        int cls = (sq ^ pxl) & 3;
        if (lact)
          *(half8v*)&sB[(r * 66 + pxl) * 32 + cls * 8] = v;
      }
      __syncthreads();
    }

    #pragma unroll 1
    for (int tap = 0; tap < 9; ++tap) {
      const int dy = tap / 3, dx = tap - 3 * (tap / 3);
      half8v ah[NOF], aq[NAQ];
      const _Float16* hp = wHi + ((size_t)tap * OC + oc0 + ocl) * CIN + cc + k8;
      #pragma unroll
      for (int j = 0; j < NOF; ++j)
        ah[j] = *(const half8v*)(hp + (size_t)j * 16 * CIN);
      if constexpr (SPLIT == 3) {
        const _Float16* lp = wLo + ((size_t)tap * OC + oc0 + ocl) * CIN + cc + k8;
        #pragma unroll
        for (int j = 0; j < NOF; ++j)
          aq[j] = *(const half8v*)(lp + (size_t)j * 16 * CIN);
      }
      const int px = ocl + dx;
      if constexpr (SPLIT == 3) {
        const int rbase = ((wv + dy) * 66 + px) * 64;
        const int clsH = (l >> 4) ^ (px & 7);
        const int clsQ = ((l >> 4) + 4) ^ (px & 7);
        __builtin_amdgcn_s_setprio(1);
        #pragma unroll
        for (int f = 0; f < 4; ++f) {
          half8v bh = *(const half8v*)&sB[rbase + f * 1024 + clsH * 8];
          half8v bq = *(const half8v*)&sB[rbase + f * 1024 + clsQ * 8];
          #pragma unroll
          for (int j = 0; j < NOF; ++j) {
            accP[j][f] = __builtin_amdgcn_mfma_f32_16x16x32_f16(ah[j], bh, accP[j][f], 0, 0, 0);
            accQ[j][f] = __builtin_amdgcn_mfma_f32_16x16x32_f16(ah[j], bq, accQ[j][f], 0, 0, 0);
            accQ[j][f] = __builtin_amdgcn_mfma_f32_16x16x32_f16(aq[j], bh, accQ[j][f], 0, 0, 0);
          }
        }
        __builtin_amdgcn_s_setprio(0);
      } else {
        const int rbase = ((wv + dy) * 66 + px) * 32;
        const int clsH = ((l >> 4) ^ px) & 3;
        __builtin_amdgcn_s_setprio(1);
        #pragma unroll
        for (int f = 0; f < 4; ++f) {
          half8v bh = *(const half8v*)&sB[rbase + f * 512 + clsH * 8];
          #pragma unroll
          for (int j = 0; j < NOF; ++j)
            accP[j][f] = __builtin_amdgcn_mfma_f32_16x16x32_f16(ah[j], bh, accP[j][f], 0, 0, 0);
        }
        __builtin_amdgcn_s_setprio(0);
      }
    }
  }

  // ---- epilogue: D col=l&15 (px), row=(l>>4)*4+reg (oc) ----
  #pragma unroll
  for (int j = 0; j < NOF; ++j)
    #pragma unroll
    for (int f = 0; f < 4; ++f) {
      const int px  = x0 + f * 16 + ocl;
      const int occ = oc0 + j * 16 + (l >> 4) * 4;
      float vv4[4];
      #pragma unroll
      for (int r = 0; r < 4; ++r) {
        float bv = bias ? bias[occ + r] : 0.f;
        float vv = accP[j][f][r] + bv;
        if constexpr (SPLIT == 3) vv += accQ[j][f][r] * (1.0f / 2048.0f);
        vv4[r] = apply_act<ACT>(vv);
      }
      if constexpr (OMODE == 0) {
        #pragma unroll
        for (int r = 0; r < 4; ++r)
          outF[((size_t)(b * OC + occ + r) * H + rowy) * W + px] = vv4[r];
      } else if constexpr (OMODE == 1) {
        // packed-padded hi/lo record
        __attribute__((aligned(8))) _Float16 hv[4], lv[4];
        #pragma unroll
        for (int r = 0; r < 4; ++r) {
          _Float16 h = (_Float16)vv4[r];
          hv[r] = h;
          lv[r] = (_Float16)((vv4[r] - (float)h) * 2048.0f);
        }
        size_t rec = ((size_t)b * PW + rowy + 1) * PW + px + 1;
        *(half4v*)&oH[rec * 64 + occ]      = *(half4v*)&hv[0];
        *(half4v*)&oH[rec * 64 + 32 + occ] = *(half4v*)&lv[0];
      } else {
        // OMODE == 3: NHWC f16 hi only
        __attribute__((aligned(8))) _Float16 hv[4];
        #pragma unroll
        for (int r = 0; r < 4; ++r) hv[r] = (_Float16)vv4[r];
        size_t ob = ((size_t)b * HW + (size_t)rowy * W + px) * OC + occ;
        *(half4v*)&oH[ob] = *(half4v*)&hv[0];
      }
    }
}

// ---------- 1x1 conv: NHWC f16 in -> chunked NHWC f16 out (hi only) ----------
template<int CIN, int OCB, int ACT>
__global__ __launch_bounds__(256)
void conv1x1_nhwc_k(const _Float16* __restrict__ in, const float* __restrict__ w,
                    _Float16* __restrict__ oH, int OC)
{
  __shared__ __align__(16) float sW[OCB][CIN];
  const int b   = blockIdx.y;
  const int oc0 = blockIdx.z * OCB;
  for (int t = threadIdx.x; t < OCB * CIN; t += 256)
    sW[t / CIN][t % CIN] = w[(size_t)(oc0 + t / CIN) * CIN + (t % CIN)];
  __syncthreads();

  const int pb = blockIdx.x * 1024 + threadIdx.x;    // 4 px at stride 256
  float acc[OCB][4];
  #pragma unroll
  for (int o = 0; o < OCB; ++o)
    #pragma unroll
    for (int i = 0; i < 4; ++i) acc[o][i] = 0.f;

  #pragma unroll 1
  for (int c0 = 0; c0 < CIN; c0 += 8) {
    float v[4][8];
    #pragma unroll
    for (int i = 0; i < 4; ++i) {
      const _Float16* ip = in + ((size_t)b * HW + pb + i * 256) * CIN + c0;
      half8v hv8 = *(const half8v*)ip;
      #pragma unroll
      for (int j = 0; j < 8; ++j) v[i][j] = (float)hv8[j];
    }
    #pragma unroll
    for (int o = 0; o < OCB; ++o) {
      const float4 w0 = *(const float4*)&sW[o][c0];
      const float4 w1 = *(const float4*)&sW[o][c0 + 4];
      #pragma unroll
      for (int i = 0; i < 4; ++i) {
        acc[o][i] += v[i][0]*w0.x + v[i][1]*w0.y + v[i][2]*w0.z + v[i][3]*w0.w
                   + v[i][4]*w1.x + v[i][5]*w1.y + v[i][6]*w1.z + v[i][7]*w1.w;
      }
    }
  }
  #pragma unroll
  for (int i = 0; i < 4; ++i) {
    __attribute__((aligned(16))) _Float16 hv[OCB];
    #pragma unroll
    for (int o = 0; o < OCB; ++o)
      hv[o] = (_Float16)apply_act<ACT>(acc[o][i]);
    size_t ob = ((size_t)(b * (OC >> 5) + (oc0 >> 5)) * HW + pb + i * 256) * 32 + (oc0 & 31);
    #pragma unroll
    for (int j = 0; j < OCB / 8; ++j)
      *(half8v*)&oH[ob + j * 8] = *(half8v*)&hv[j * 8];
  }
}

// ---------- corr + top-3, 2 px/thread float2 (jax tie-break: lower index wins) ----------
__global__ __launch_bounds__(256)
void corr_topk_k(const float* __restrict__ warp, const float* __restrict__ x,
                 int* __restrict__ idxo)
{
  const int p2 = (blockIdx.x * 256 + threadIdx.x) * 2;
  const int b = blockIdx.y;
  float corr[9][2];
  #pragma unroll
  for (int o = 0; o < 9; ++o) { corr[o][0] = 0.f; corr[o][1] = 0.f; }
  #pragma unroll 1
  for (int c = 0; c < 32; ++c) {
    float2 xv = *(const float2*)&x[((size_t)b * 32 + c) * HW + p2];
    const float* wp = warp + ((size_t)b * 288 + (size_t)c * 9) * HW + p2;
    #pragma unroll
    for (int o = 0; o < 9; ++o) {
      float2 wv = *(const float2*)&wp[(size_t)o * HW];
      corr[o][0] += wv.x * xv.x;
      corr[o][1] += wv.y * xv.y;
    }
  }
  int2 packs;
  #pragma unroll
  for (int i = 0; i < 2; ++i) {
    unsigned mask = 0;
    int packed = 0;
    #pragma unroll
    for (int t = 0; t < 3; ++t) {
      float best = -INFINITY; int bi = 0;
      #pragma unroll
      for (int o = 0; o < 9; ++o) {
        bool take = (((mask >> o) & 1u) == 0u) && (corr[o][i] > best);
        best = take ? corr[o][i] : best;
        bi   = take ? o          : bi;
      }
      mask   |= 1u << bi;
      packed |= bi << (4 * t);
    }
    ((int*)&packs)[i] = packed;
  }
  *(int2*)&idxo[(size_t)b * HW + p2] = packs;
}

// ---------- gather selected warps + 3x3 conv with w_sel; out 32-ch NHWC f16 (hi only) ----------
__global__ __launch_bounds__(256)
void selconv_k(const float* __restrict__ warp, const int* __restrict__ idxp,
               const float* __restrict__ wsel, const float* __restrict__ bsel,
               _Float16* __restrict__ oH)
{
  const int tx = threadIdx.x & 31, ty = threadIdx.x >> 5;
  const int px = blockIdx.x * 32 + tx;
  const int py = blockIdx.y * 8 + ty;
  const int b  = blockIdx.z;

  int  nidx[9];
  bool nval[9];
  int  qoff[9];
  #pragma unroll
  for (int kh = 0; kh < 3; ++kh)
    #pragma unroll
    for (int kw = 0; kw < 3; ++kw) {
      int k = kh * 3 + kw;
      int qy = py + kh - 1, qx = px + kw - 1;
      nval[k] = (qy >= 0 && qy < H && qx >= 0 && qx < W);
      qoff[k] = qy * W + qx;
      nidx[k] = nval[k] ? idxp[(size_t)b * HW + qoff[k]] : 0;
    }

  float ws27[27];
  #pragma unroll
  for (int i = 0; i < 27; ++i) ws27[i] = wsel[i];
  const float bs = bsel[0];

  float arr[32];
  #pragma unroll 1
  for (int c = 0; c < 32; ++c) {
    float acc = bs;
    const float* wb = warp + ((size_t)b * 288 + (size_t)c * 9) * HW;
    #pragma unroll
    for (int k = 0; k < 9; ++k) {
      if (nval[k]) {
        int pk = nidx[k];
        #pragma unroll
        for (int t = 0; t < 3; ++t) {
          int o = (pk >> (4 * t)) & 15;
          acc += ws27[t * 9 + k] * wb[(size_t)o * HW + qoff[k]];
        }
      }
    }
    arr[c] = acc;
  }

  __attribute__((aligned(16))) _Float16 hv[32];
  #pragma unroll
  for (int c = 0; c < 32; ++c) hv[c] = (_Float16)arr[c];
  size_t ob = ((size_t)b * HW + (size_t)py * W + px) * 32;
  #pragma unroll
  for (int j = 0; j < 4; ++j)
    *(half8v*)&oH[ob + j * 8] = *(half8v*)&hv[j * 8];
}

// ---------- launch ----------
extern "C" void kernel_launch(void* const* d_in, const int* in_sizes, int n_in,
                              void* d_out, int out_size, void* d_ws, size_t ws_size,
                              hipStream_t stream) {
  const float* x      = (const float*)d_in[0];
  const float* key    = (const float*)d_in[1];
  const float* w_off1 = (const float*)d_in[2];
  const float* b_off1 = (const float*)d_in[3];
  const float* w_off2 = (const float*)d_in[4];
  const float* b_off2 = (const float*)d_in[5];
  const float* w_dcn  = (const float*)d_in[6];
  const float* b_dcn  = (const float*)d_in[7];
  const float* w_sel  = (const float*)d_in[8];
  const float* b_sel  = (const float*)d_in[9];
  const float* w_t1   = (const float*)d_in[10];
  const float* w_t2   = (const float*)d_in[11];
  const float* w_t3   = (const float*)d_in[12];
  const float* w_t4   = (const float*)d_in[13];
  const float* w_t5   = (const float*)d_in[14];

  // ---- workspace layout (peak ~185.74 MB) ----
  // packed-padded buffer size per instance: 2 batches * 258*258 * 64 halves * 2B = 17,040,384 B
  char* ws = (char*)d_ws;
  float* warp = (float*)(ws);                                // [2,288,HW] f32 NCHW, [0, 150994944)
  // pre-dcn inside warp region:
  _Float16* xP   = (_Float16*)(ws);                          // [0, 17040384)
  _Float16* o1P  = (_Float16*)(ws + 17040384);               // [17040384, 34080768)
  _Float16* w1H  = (_Float16*)(ws + 34080768);               // phase-1 off tables
  _Float16* w1L  = w1H + 18432;
  _Float16* w2H  = w1L + 18432;
  _Float16* w2L  = w2H + 9216;
  // outside warp region:
  _Float16* wdH  = (_Float16*)(ws + 150994944);              // dcn tables (663,552 B)
  _Float16* wdL  = wdH + 165888;
  _Float16* keyP = (_Float16*)(ws + 151658496);              // [151658496, 168698880)
  _Float16* o2P  = (_Float16*)(ws + 168698880);              // [168698880, 185739264)
  // post-dcn (wd/keyP dead):
  int*      idxb = (int*)(ws + 150994944);                   // over wd tables
  _Float16* kwH  = (_Float16*)(ws + 151658496);              // selconv out hi, 8.4 MB (over keyP)
  _Float16* twB  = (_Float16*)(ws + 160047104);              // tail tables (over keyP tail)
  _Float16* t1H_w = twB;
  _Float16* t1L_w = twB + 9216;
  _Float16* t3H_w = twB + 18432;
  _Float16* t3L_w = twB + 165888;
  _Float16* t5H_w = twB + 313344;
  _Float16* t5L_w = twB + 322560;
  // tail activations inside dead warp region:
  _Float16* y1  = (_Float16*)(ws);                           // t1 out NHWC f16 [2,HW,32]
  _Float16* t2H = (_Float16*)(ws + 16777216);                // chunked [2,4,HW,32] f16
  _Float16* t4H = (_Float16*)(ws + 50331648);
  _Float16* y3  = (_Float16*)(ws + 83886080);                // t3 out NHWC f16 [2,HW,128]
  float* out = (float*)d_out;

  dim3 blk(256);

  // zero packed borders (x, key, off1, off2), then pack interiors
  zero_border_k<<<dim3(5, 8), blk, 0, stream>>>(xP, keyP, o1P, o2P);
  pack2_k<<<dim3(256, 2, 2), blk, 0, stream>>>(x, xP, key, keyP);
  // phase-1 weight tables
  prep3_w_k<<<dim3(756), blk, 0, stream>>>(
      w_off1, w1H, w1L, 32, 64, 72,
      w_off2, w2H, w2L, 32, 32, 36,
      w_dcn,  wdH, wdL, 288, 64);

  // off1 = lrelu(conv(concat(x,key)))  -> packed-padded   [split-3]
  conv3x3_mfma_k<64, 32, 32, 1, 1, 3><<<dim3(512), blk, 0, stream>>>(
      xP, nullptr, keyP, nullptr, 32, w1H, w1L, b_off1, nullptr, o1P, nullptr);
  // off2 = lrelu(conv(off1))           -> packed-padded   [split-3]
  conv3x3_mfma_k<32, 32, 32, 1, 1, 3><<<dim3(512), blk, 0, stream>>>(
      o1P, nullptr, nullptr, nullptr, 32, w2H, w2L, b_off2, nullptr, o2P, nullptr);
  // warp = conv(concat(key,off2))      -> NCHW f32        [split-3]
  conv3x3_mfma_k<64, 288, 32, 0, 0, 3><<<dim3(4608), blk, 0, stream>>>(
      keyP, nullptr, o2P, nullptr, 32, wdH, wdL, b_dcn, warp, nullptr, nullptr);
  // corr + top-3
  corr_topk_k<<<dim3(128, 2), blk, 0, stream>>>(warp, x, idxb);
  // key_warp -> f16 hi
  selconv_k<<<dim3(8, 32, 2), blk, 0, stream>>>(warp, idxb, w_sel, b_sel, kwH);

  // phase-2 weight tables
  prep3_w_k<<<dim3(648), blk, 0, stream>>>(
      w_t1, t1H_w, t1L_w, 32, 32, 36,
      w_t3, t3H_w, t3L_w, 128, 128, 576,
      w_t5, t5H_w, t5L_w, 32, 32);

  // t1: conv3x3 (gelu) -> NHWC f16 y1            [single-f16]
  conv3x3_mfma_k<32, 32, 32, 2, 3, 1><<<dim3(512), blk, 0, stream>>>(
      kwH, nullptr, nullptr, nullptr, 32, t1H_w, t1L_w, nullptr, nullptr, y1, nullptr);
  // t2: 1x1 (gelu) -> chunked f16 hi [2,4,HW,32]
  conv1x1_nhwc_k<32, 16, 2><<<dim3(64, 2, 8), blk, 0, stream>>>(y1, w_t2, t2H, 128);
  // t3: conv3x3 (gelu) -> NHWC f16 y3            [single-f16, OCB=64]
  conv3x3_mfma_k<128, 128, 64, 2, 3, 1><<<dim3(1024), blk, 0, stream>>>(
      t2H, nullptr, nullptr, nullptr, 128, t3H_w, t3L_w, nullptr, nullptr, y3, nullptr);
  // t4: 1x1 (gelu) -> f16 hi
  conv1x1_nhwc_k<128, 16, 2><<<dim3(64, 2, 2), blk, 0, stream>>>(y3, w_t4, t4H, 32);
  // t5: conv3x3 -> NCHW f32 final                [single-f16]
  conv3x3_mfma_k<32, 32, 32, 0, 0, 1><<<dim3(512), blk, 0, stream>>>(
      t4H, nullptr, nullptr, nullptr, 32, t5H_w, t5L_w, nullptr, out, nullptr, nullptr);
}

// Round 18
// 601.259 us; speedup vs baseline: 1.4315x; 1.0079x over previous
//
#include <hip/hip_runtime.h>
#include <math.h>

static constexpr int H = 256, W = 256, HW = H * W;
static constexpr int PW = 258;
static constexpr size_t PREC = 66564;   // 258*258 padded px

typedef __attribute__((ext_vector_type(8))) _Float16 half8v;  // 16B
typedef __attribute__((ext_vector_type(4))) _Float16 half4v;  // 8B
typedef __attribute__((ext_vector_type(4))) float  float4v;   // MFMA acc

__device__ __forceinline__ half8v h8zero() {
  half8v z;
  #pragma unroll
  for (int i = 0; i < 8; ++i) z[i] = (_Float16)0;
  return z;
}

// global_load_lds: per-lane global src (16B), wave-uniform LDS base; lane i -> base + i*16.
__device__ __forceinline__ void gload_lds16(const _Float16* g, _Float16* lds) {
  __builtin_amdgcn_global_load_lds(
      (const __attribute__((address_space(1))) void*)g,
      (__attribute__((address_space(3))) void*)lds, 16, 0, 0);
}

// ---------- activations ----------
__device__ __forceinline__ float gelu_f(float v) {
  return 0.5f * v * (1.0f + erff(v * 0.70710678118654752440f));
}
template<int ACT>
__device__ __forceinline__ float apply_act(float v) {
  if constexpr (ACT == 1) return v >= 0.f ? v : 0.1f * v;   // LeakyReLU(0.1)
  if constexpr (ACT == 2) return gelu_f(v);
  return v;
}

// ---------- zero 1-px borders, REC=64 packed buffers (4 bufs x 2 batches) ----------
__global__ __launch_bounds__(256)
void zero_border64_k(_Float16* p0, _Float16* p1, _Float16* p2, _Float16* p3)
{
  int t = blockIdx.x * 256 + threadIdx.x;
  if (t >= 1028) return;
  int inst = blockIdx.y;
  _Float16* P = (inst >> 1) == 0 ? p0 : ((inst >> 1) == 1 ? p1 : ((inst >> 1) == 2 ? p2 : p3));
  int b = inst & 1;
  int y, x;
  if      (t < 258) { y = 0;        x = t; }
  else if (t < 516) { y = 257;      x = t - 258; }
  else if (t < 772) { y = t - 515;  x = 0; }
  else              { y = t - 771;  x = 257; }
  _Float16* o = P + ((size_t)b * PREC + (size_t)y * PW + x) * 64;
  half8v z = h8zero();
  #pragma unroll
  for (int j = 0; j < 8; ++j) *(half8v*)&o[j * 8] = z;
}

// ---------- zero 1-px borders, REC=32 packed buffers (4 bufs x 2 batches; per-buf batch stride in recs) ----------
__global__ __launch_bounds__(256)
void zero_border32_k(_Float16* p0, size_t s0, _Float16* p1, size_t s1,
                     _Float16* p2, size_t s2, _Float16* p3, size_t s3)
{
  int t = blockIdx.x * 256 + threadIdx.x;
  if (t >= 1028) return;
  int inst = blockIdx.y;
  _Float16* P; size_t bs;
  switch (inst >> 1) {
    case 0: P = p0; bs = s0; break;
    case 1: P = p1; bs = s1; break;
    case 2: P = p2; bs = s2; break;
    default: P = p3; bs = s3; break;
  }
  int b = inst & 1;
  int y, x;
  if      (t < 258) { y = 0;        x = t; }
  else if (t < 516) { y = 257;      x = t - 258; }
  else if (t < 772) { y = t - 515;  x = 0; }
  else              { y = t - 771;  x = 257; }
  _Float16* o = P + ((size_t)b * bs + (size_t)y * PW + x) * 32;
  half8v z = h8zero();
  #pragma unroll
  for (int j = 0; j < 4; ++j) *(half8v*)&o[j * 8] = z;
}

// ---------- pack x,key: NCHW f32 -> packed-padded [B][258][258][64]: hi(0..31)+lo(32..63) ----------
__global__ __launch_bounds__(256)
void pack2_k(const float* __restrict__ inA, _Float16* __restrict__ pA,
             const float* __restrict__ inB, _Float16* __restrict__ pB)
{
  const int p = blockIdx.x * 256 + threadIdx.x;
  const int b = blockIdx.y;
  const float* in = blockIdx.z ? inB : inA;
  _Float16* P = blockIdx.z ? pB : pA;
  const float* ip = in + (size_t)b * 32 * HW + p;
  __attribute__((aligned(16))) _Float16 hv[32], lv[32];
  #pragma unroll
  for (int c = 0; c < 32; ++c) {
    float v = ip[(size_t)c * HW];
    _Float16 h = (_Float16)v;
    hv[c] = h;
    lv[c] = (_Float16)((v - (float)h) * 2048.0f);
  }
  const int y = p >> 8, xcol = p & 255;
  _Float16* o = P + ((size_t)b * PREC + (size_t)(y + 1) * PW + xcol + 1) * 64;
  #pragma unroll
  for (int j = 0; j < 4; ++j) {
    *(half8v*)&o[j * 8]      = *(half8v*)&hv[j * 8];
    *(half8v*)&o[32 + j * 8] = *(half8v*)&lv[j * 8];
  }
}

// ---------- weight prep x3: [OC][CIN][3][3] f32 -> [tap][OC][CIN] f16 hi + scaled lo ----------
__device__ __forceinline__ void prep_w_body(const float* w, _Float16* hi, _Float16* lo,
                                            int OC, int CIN, int tid)
{
  if (tid >= OC * CIN * 9) return;
  int ci = tid % CIN; int r = tid / CIN; int oc = r % OC; int tap = r / OC;
  float v = w[((size_t)oc * CIN + ci) * 9 + tap];
  _Float16 h = (_Float16)v;
  hi[tid] = h;
  lo[tid] = (_Float16)((v - (float)h) * 2048.0f);
}
__global__ __launch_bounds__(256)
void prep3_w_k(const float* __restrict__ w0, _Float16* __restrict__ h0, _Float16* __restrict__ l0, int OC0, int CIN0, int nb0,
               const float* __restrict__ w1, _Float16* __restrict__ h1, _Float16* __restrict__ l1, int OC1, int CIN1, int nb1,
               const float* __restrict__ w2, _Float16* __restrict__ h2, _Float16* __restrict__ l2, int OC2, int CIN2)
{
  int bb = blockIdx.x;
  if (bb < nb0)            prep_w_body(w0, h0, l0, OC0, CIN0, bb * 256 + threadIdx.x);
  else if (bb < nb0 + nb1) prep_w_body(w1, h1, l1, OC1, CIN1, (bb - nb0) * 256 + threadIdx.x);
  else                     prep_w_body(w2, h2, l2, OC2, CIN2, (bb - nb0 - nb1) * 256 + threadIdx.x);
}

// ---------- 3x3 conv, f16 MFMA; ALL inputs packed-padded, ALL staging via global_load_lds ----------
// SPLIT=3 (pre-topk): [.][258][258][64] hi+lo records; 48 gll tasks (8 px x 8 slots,
//   pre-swizzled granule m=(l&7)^(l>>3)) + 2-px edge copies. HW-verified r17.
// SPLIT=1 (tail): [.][258][258][32] hi records; 24 gll tasks (16 px x 4 slots,
//   pre-swizzled granule (l&3)^((l>>2)&3)) + 2-px edge copies. Same equivalence.
// OMODE: 0 = NCHW f32 out, 1 = packed-padded hi/lo out, 3 = NHWC f16 hi only.
// MFMA 16x16x32 f16 (HW-verified r5-r17): A row=l&15 (oc), k=(l>>4)*8+j;
//   B col=l&15 (px); D col=l&15 (px), row=(l>>4)*4+reg (oc).
template<int CIN, int OC, int OCB, int ACT, int OMODE, int SPLIT>
__global__ __launch_bounds__(256)
void conv3x3_mfma_k(const _Float16* __restrict__ iH0, const _Float16* __restrict__ iL0,
                    const _Float16* __restrict__ iH1, const _Float16* __restrict__ iL1, int cin0,
                    const _Float16* __restrict__ wHi, const _Float16* __restrict__ wLo,
                    const float* __restrict__ bias,
                    float* __restrict__ outF, _Float16* __restrict__ oH, _Float16* __restrict__ oL)
{
  constexpr int NOF  = OCB / 16;
  constexpr int NAQ  = (SPLIT == 3) ? NOF : 1;
  constexpr int REC  = (SPLIT == 3) ? 64 : 32;
  constexpr int nOcg = OC / OCB;
  __shared__ _Float16 sB[6 * 66 * REC];

  const int l  = threadIdx.x & 63;
  const int wv = threadIdx.x >> 6;

  const int bid = blockIdx.x;
  const int xcd = bid & 7, q = bid >> 3;
  const int ocg  = q % nOcg;
  const int tIdx = (q / nOcg) * 8 + xcd;
  const int b   = tIdx >> 8;
  const int x0  = ((tIdx >> 6) & 3) * 64;
  const int y0  = (tIdx & 63) * 4;
  const int oc0 = ocg * OCB;

  float4v accP[NOF][4];
  float4v accQ[NAQ][4];
  #pragma unroll
  for (int j = 0; j < NOF; ++j)
    #pragma unroll
    for (int f = 0; f < 4; ++f)
      accP[j][f] = (float4v){0.f, 0.f, 0.f, 0.f};
  #pragma unroll
  for (int j = 0; j < NAQ; ++j)
    #pragma unroll
    for (int f = 0; f < 4; ++f)
      accQ[j][f] = (float4v){0.f, 0.f, 0.f, 0.f};

  const int k8  = (l >> 4) * 8;
  const int ocl = l & 15;
  const int rowy = y0 + wv;

  #pragma unroll 1
  for (int cc = 0; cc < CIN; cc += 32) {
    if constexpr (SPLIT == 3) {
      const _Float16* cb = (cc < cin0 ? iH0 : iH1) + (size_t)b * (PREC * 64);
      __syncthreads();
      // 48 gll tasks: 6 rows x 8 px-groups (8 px x 8 slots); 12 per wave
      #pragma unroll
      for (int k = 0; k < 12; ++k) {
        int t = wv + 4 * k;
        int r = t >> 3, s = t & 7;
        const _Float16* src = cb
            + (((size_t)(y0 + r) * PW) + (x0 + s * 8 + (l >> 3))) * 64
            + ((l & 7) ^ (l >> 3)) * 8;
        gload_lds16(src, &sB[(r * 66 + s * 8) * 64]);
      }
      #pragma unroll
      for (int rr = wv; rr < 6; rr += 4) {
        if (l < 16) {
          int pxo = l >> 3, slot = l & 7;
          const _Float16* src = cb
              + (((size_t)(y0 + rr) * PW) + (x0 + 64 + pxo)) * 64 + (slot ^ pxo) * 8;
          half8v v = *(const half8v*)src;
          *(half8v*)&sB[(rr * 66 + 64 + pxo) * 64 + slot * 8] = v;
        }
      }
      __syncthreads();
    } else {
      const _Float16* cb = iH0 + (size_t)(b * (CIN >> 5) + (cc >> 5)) * (PREC * 32);
      __syncthreads();
      // 24 gll tasks: 6 rows x 4 px-groups (16 px x 4 slots); 6 per wave
      #pragma unroll
      for (int k = 0; k < 6; ++k) {
        int t = wv + 4 * k;
        int r = t >> 2, s = t & 3;
        const _Float16* src = cb
            + (((size_t)(y0 + r) * PW) + (x0 + s * 16 + (l >> 2))) * 32
            + ((l & 3) ^ ((l >> 2) & 3)) * 8;
        gload_lds16(src, &sB[(r * 66 + s * 16) * 32]);
      }
      #pragma unroll
      for (int rr = wv; rr < 6; rr += 4) {
        if (l < 8) {
          int pxo = l >> 2, slot = l & 3;
          const _Float16* src = cb
              + (((size_t)(y0 + rr) * PW) + (x0 + 64 + pxo)) * 32 + (slot ^ pxo) * 8;
          half8v v = *(const half8v*)src;
          *(half8v*)&sB[(rr * 66 + 64 + pxo) * 32 + slot * 8] = v;
        }
      }
      __syncthreads();
    }

    #pragma unroll 1
    for (int tap = 0; tap < 9; ++tap) {
      const int dy = tap / 3, dx = tap - 3 * (tap / 3);
      half8v ah[NOF], aq[NAQ];
      const _Float16* hp = wHi + ((size_t)tap * OC + oc0 + ocl) * CIN + cc + k8;
      #pragma unroll
      for (int j = 0; j < NOF; ++j)
        ah[j] = *(const half8v*)(hp + (size_t)j * 16 * CIN);
      if constexpr (SPLIT == 3) {
        const _Float16* lp = wLo + ((size_t)tap * OC + oc0 + ocl) * CIN + cc + k8;
        #pragma unroll
        for (int j = 0; j < NOF; ++j)
          aq[j] = *(const half8v*)(lp + (size_t)j * 16 * CIN);
      }
      const int px = ocl + dx;
      if constexpr (SPLIT == 3) {
        const int rbase = ((wv + dy) * 66 + px) * 64;
        const int clsH = (l >> 4) ^ (px & 7);
        const int clsQ = ((l >> 4) + 4) ^ (px & 7);
        __builtin_amdgcn_s_setprio(1);
        #pragma unroll
        for (int f = 0; f < 4; ++f) {
          half8v bh = *(const half8v*)&sB[rbase + f * 1024 + clsH * 8];
          half8v bq = *(const half8v*)&sB[rbase + f * 1024 + clsQ * 8];
          #pragma unroll
          for (int j = 0; j < NOF; ++j) {
            accP[j][f] = __builtin_amdgcn_mfma_f32_16x16x32_f16(ah[j], bh, accP[j][f], 0, 0, 0);
            accQ[j][f] = __builtin_amdgcn_mfma_f32_16x16x32_f16(ah[j], bq, accQ[j][f], 0, 0, 0);
            accQ[j][f] = __builtin_amdgcn_mfma_f32_16x16x32_f16(aq[j], bh, accQ[j][f], 0, 0, 0);
          }
        }
        __builtin_amdgcn_s_setprio(0);
      } else {
        const int rbase = ((wv + dy) * 66 + px) * 32;
        const int clsH = ((l >> 4) ^ px) & 3;
        __builtin_amdgcn_s_setprio(1);
        #pragma unroll
        for (int f = 0; f < 4; ++f) {
          half8v bh = *(const half8v*)&sB[rbase + f * 512 + clsH * 8];
          #pragma unroll
          for (int j = 0; j < NOF; ++j)
            accP[j][f] = __builtin_amdgcn_mfma_f32_16x16x32_f16(ah[j], bh, accP[j][f], 0, 0, 0);
        }
        __builtin_amdgcn_s_setprio(0);
      }
    }
  }

  // ---- epilogue: D col=l&15 (px), row=(l>>4)*4+reg (oc) ----
  #pragma unroll
  for (int j = 0; j < NOF; ++j)
    #pragma unroll
    for (int f = 0; f < 4; ++f) {
      const int px  = x0 + f * 16 + ocl;
      const int occ = oc0 + j * 16 + (l >> 4) * 4;
      float vv4[4];
      #pragma unroll
      for (int r = 0; r < 4; ++r) {
        float bv = bias ? bias[occ + r] : 0.f;
        float vv = accP[j][f][r] + bv;
        if constexpr (SPLIT == 3) vv += accQ[j][f][r] * (1.0f / 2048.0f);
        vv4[r] = apply_act<ACT>(vv);
      }
      if constexpr (OMODE == 0) {
        #pragma unroll
        for (int r = 0; r < 4; ++r)
          outF[((size_t)(b * OC + occ + r) * H + rowy) * W + px] = vv4[r];
      } else if constexpr (OMODE == 1) {
        __attribute__((aligned(8))) _Float16 hv[4], lv[4];
        #pragma unroll
        for (int r = 0; r < 4; ++r) {
          _Float16 h = (_Float16)vv4[r];
          hv[r] = h;
          lv[r] = (_Float16)((vv4[r] - (float)h) * 2048.0f);
        }
        size_t rec = (size_t)b * PREC + (size_t)(rowy + 1) * PW + px + 1;
        *(half4v*)&oH[rec * 64 + occ]      = *(half4v*)&hv[0];
        *(half4v*)&oH[rec * 64 + 32 + occ] = *(half4v*)&lv[0];
      } else {
        // OMODE == 3: NHWC f16 hi only (linear)
        __attribute__((aligned(8))) _Float16 hv[4];
        #pragma unroll
        for (int r = 0; r < 4; ++r) hv[r] = (_Float16)vv4[r];
        size_t ob = ((size_t)b * HW + (size_t)rowy * W + px) * OC + occ;
        *(half4v*)&oH[ob] = *(half4v*)&hv[0];
      }
    }
}

// ---------- 1x1 conv: NHWC f16 in -> packed-padded chunked f16 hi out ----------
template<int CIN, int OCB, int ACT>
__global__ __launch_bounds__(256)
void conv1x1_nhwc_k(const _Float16* __restrict__ in, const float* __restrict__ w,
                    _Float16* __restrict__ oP, int OC)
{
  __shared__ __align__(16) float sW[OCB][CIN];
  const int b   = blockIdx.y;
  const int oc0 = blockIdx.z * OCB;
  for (int t = threadIdx.x; t < OCB * CIN; t += 256)
    sW[t / CIN][t % CIN] = w[(size_t)(oc0 + t / CIN) * CIN + (t % CIN)];
  __syncthreads();

  const int pb = blockIdx.x * 1024 + threadIdx.x;    // 4 px at stride 256
  float acc[OCB][4];
  #pragma unroll
  for (int o = 0; o < OCB; ++o)
    #pragma unroll
    for (int i = 0; i < 4; ++i) acc[o][i] = 0.f;

  #pragma unroll 1
  for (int c0 = 0; c0 < CIN; c0 += 8) {
    float v[4][8];
    #pragma unroll
    for (int i = 0; i < 4; ++i) {
      const _Float16* ip = in + ((size_t)b * HW + pb + i * 256) * CIN + c0;
      half8v hv8 = *(const half8v*)ip;
      #pragma unroll
      for (int j = 0; j < 8; ++j) v[i][j] = (float)hv8[j];
    }
    #pragma unroll
    for (int o = 0; o < OCB; ++o) {
      const float4 w0 = *(const float4*)&sW[o][c0];
      const float4 w1 = *(const float4*)&sW[o][c0 + 4];
      #pragma unroll
      for (int i = 0; i < 4; ++i) {
        acc[o][i] += v[i][0]*w0.x + v[i][1]*w0.y + v[i][2]*w0.z + v[i][3]*w0.w
                   + v[i][4]*w1.x + v[i][5]*w1.y + v[i][6]*w1.z + v[i][7]*w1.w;
      }
    }
  }
  #pragma unroll
  for (int i = 0; i < 4; ++i) {
    __attribute__((aligned(16))) _Float16 hv[OCB];
    #pragma unroll
    for (int o = 0; o < OCB; ++o)
      hv[o] = (_Float16)apply_act<ACT>(acc[o][i]);
    int p = pb + i * 256;
    int y = p >> 8, xcol = p & 255;
    size_t rec = (size_t)(b * (OC >> 5) + (oc0 >> 5)) * PREC + (size_t)(y + 1) * PW + xcol + 1;
    #pragma unroll
    for (int j = 0; j < OCB / 8; ++j)
      *(half8v*)&oP[rec * 32 + (oc0 & 31) + j * 8] = *(half8v*)&hv[j * 8];
  }
}

// ---------- corr + top-3, 2 px/thread float2 (jax tie-break: lower index wins) ----------
__global__ __launch_bounds__(256)
void corr_topk_k(const float* __restrict__ warp, const float* __restrict__ x,
                 int* __restrict__ idxo)
{
  const int p2 = (blockIdx.x * 256 + threadIdx.x) * 2;
  const int b = blockIdx.y;
  float corr[9][2];
  #pragma unroll
  for (int o = 0; o < 9; ++o) { corr[o][0] = 0.f; corr[o][1] = 0.f; }
  #pragma unroll 1
  for (int c = 0; c < 32; ++c) {
    float2 xv = *(const float2*)&x[((size_t)b * 32 + c) * HW + p2];
    const float* wp = warp + ((size_t)b * 288 + (size_t)c * 9) * HW + p2;
    #pragma unroll
    for (int o = 0; o < 9; ++o) {
      float2 wv = *(const float2*)&wp[(size_t)o * HW];
      corr[o][0] += wv.x * xv.x;
      corr[o][1] += wv.y * xv.y;
    }
  }
  int2 packs;
  #pragma unroll
  for (int i = 0; i < 2; ++i) {
    unsigned mask = 0;
    int packed = 0;
    #pragma unroll
    for (int t = 0; t < 3; ++t) {
      float best = -INFINITY; int bi = 0;
      #pragma unroll
      for (int o = 0; o < 9; ++o) {
        bool take = (((mask >> o) & 1u) == 0u) && (corr[o][i] > best);
        best = take ? corr[o][i] : best;
        bi   = take ? o          : bi;
      }
      mask   |= 1u << bi;
      packed |= bi << (4 * t);
    }
    ((int*)&packs)[i] = packed;
  }
  *(int2*)&idxo[(size_t)b * HW + p2] = packs;
}

// ---------- gather selected warps + 3x3 conv with w_sel; out packed-padded f16 hi ----------
__global__ __launch_bounds__(256)
void selconv_k(const float* __restrict__ warp, const int* __restrict__ idxp,
               const float* __restrict__ wsel, const float* __restrict__ bsel,
               _Float16* __restrict__ oP)
{
  const int tx = threadIdx.x & 31, ty = threadIdx.x >> 5;
  const int px = blockIdx.x * 32 + tx;
  const int py = blockIdx.y * 8 + ty;
  const int b  = blockIdx.z;

  int  nidx[9];
  bool nval[9];
  int  qoff[9];
  #pragma unroll
  for (int kh = 0; kh < 3; ++kh)
    #pragma unroll
    for (int kw = 0; kw < 3; ++kw) {
      int k = kh * 3 + kw;
      int qy = py + kh - 1, qx = px + kw - 1;
      nval[k] = (qy >= 0 && qy < H && qx >= 0 && qx < W);
      qoff[k] = qy * W + qx;
      nidx[k] = nval[k] ? idxp[(size_t)b * HW + qoff[k]] : 0;
    }

  float ws27[27];
  #pragma unroll
  for (int i = 0; i < 27; ++i) ws27[i] = wsel[i];
  const float bs = bsel[0];

  float arr[32];
  #pragma unroll 1
  for (int c = 0; c < 32; ++c) {
    float acc = bs;
    const float* wb = warp + ((size_t)b * 288 + (size_t)c * 9) * HW;
    #pragma unroll
    for (int k = 0; k < 9; ++k) {
      if (nval[k]) {
        int pk = nidx[k];
        #pragma unroll
        for (int t = 0; t < 3; ++t) {
          int o = (pk >> (4 * t)) & 15;
          acc += ws27[t * 9 + k] * wb[(size_t)o * HW + qoff[k]];
        }
      }
    }
    arr[c] = acc;
  }

  __attribute__((aligned(16))) _Float16 hv[32];
  #pragma unroll
  for (int c = 0; c < 32; ++c) hv[c] = (_Float16)arr[c];
  size_t rec = (size_t)b * PREC + (size_t)(py + 1) * PW + px + 1;
  #pragma unroll
  for (int j = 0; j < 4; ++j)
    *(half8v*)&oP[rec * 32 + j * 8] = *(half8v*)&hv[j * 8];
}

// ---------- launch ----------
extern "C" void kernel_launch(void* const* d_in, const int* in_sizes, int n_in,
                              void* d_out, int out_size, void* d_ws, size_t ws_size,
                              hipStream_t stream) {
  const float* x      = (const float*)d_in[0];
  const float* key    = (const float*)d_in[1];
  const float* w_off1 = (const float*)d_in[2];
  const float* b_off1 = (const float*)d_in[3];
  const float* w_off2 = (const float*)d_in[4];
  const float* b_off2 = (const float*)d_in[5];
  const float* w_dcn  = (const float*)d_in[6];
  const float* b_dcn  = (const float*)d_in[7];
  const float* w_sel  = (const float*)d_in[8];
  const float* b_sel  = (const float*)d_in[9];
  const float* w_t1   = (const float*)d_in[10];
  const float* w_t2   = (const float*)d_in[11];
  const float* w_t3   = (const float*)d_in[12];
  const float* w_t4   = (const float*)d_in[13];
  const float* w_t5   = (const float*)d_in[14];

  // ---- workspace layout (peak ~185.74 MB) ----
  // REC64 packed buffer: 2*66564*64*2 = 17,040,384 B. REC32: 8,520,192 B.
  char* ws = (char*)d_ws;
  float* warp = (float*)(ws);                                // [2,288,HW] f32, [0, 150994944)
  // pre-dcn inside warp region:
  _Float16* xP   = (_Float16*)(ws);                          // [0, 17040384)
  _Float16* o1P  = (_Float16*)(ws + 17040384);               // [17040384, 34080768)
  _Float16* w1H  = (_Float16*)(ws + 34080768);
  _Float16* w1L  = w1H + 18432;
  _Float16* w2H  = w1L + 18432;
  _Float16* w2L  = w2H + 9216;
  // outside warp region:
  _Float16* wdH  = (_Float16*)(ws + 150994944);              // dcn tables (663,552 B)
  _Float16* wdL  = wdH + 165888;
  _Float16* keyP = (_Float16*)(ws + 151658496);              // [151658496, 168698880)
  _Float16* o2P  = (_Float16*)(ws + 168698880);              // [168698880, 185739264)
  // post-dcn (wd/keyP dead):
  int*      idxb = (int*)(ws + 150994944);                   // over wd tables (524 KB < 663 KB)
  _Float16* kwP  = (_Float16*)(ws + 151658496);              // selconv out, 8.52 MB (over keyP)
  _Float16* twB  = (_Float16*)(ws + 160178688);              // tail tables, 663 KB (over keyP tail)
  _Float16* t1H_w = twB;
  _Float16* t1L_w = twB + 9216;
  _Float16* t3H_w = twB + 18432;
  _Float16* t3L_w = twB + 165888;
  _Float16* t5H_w = twB + 313344;
  _Float16* t5L_w = twB + 322560;
  // tail activations inside dead warp region:
  _Float16* y1  = (_Float16*)(ws);                           // NHWC f16 [2,HW,32], 8.4 MB
  _Float16* t2P = (_Float16*)(ws + 16777216);                // padded chunked [2,4,PREC,32], 34.08 MB
  _Float16* t4P = (_Float16*)(ws + 58720256);                // padded [2,PREC,32], 8.52 MB
  _Float16* y3  = (_Float16*)(ws + 83886080);                // NHWC f16 [2,HW,128], 33.6 MB
  float* out = (float*)d_out;

  dim3 blk(256);

  // zero pre-topk packed borders, pack x,key
  zero_border64_k<<<dim3(5, 8), blk, 0, stream>>>(xP, keyP, o1P, o2P);
  pack2_k<<<dim3(256, 2, 2), blk, 0, stream>>>(x, xP, key, keyP);
  prep3_w_k<<<dim3(756), blk, 0, stream>>>(
      w_off1, w1H, w1L, 32, 64, 72,
      w_off2, w2H, w2L, 32, 32, 36,
      w_dcn,  wdH, wdL, 288, 64);

  // off1 -> packed-padded [split-3]
  conv3x3_mfma_k<64, 32, 32, 1, 1, 3><<<dim3(512), blk, 0, stream>>>(
      xP, nullptr, keyP, nullptr, 32, w1H, w1L, b_off1, nullptr, o1P, nullptr);
  // off2 -> packed-padded [split-3]
  conv3x3_mfma_k<32, 32, 32, 1, 1, 3><<<dim3(512), blk, 0, stream>>>(
      o1P, nullptr, nullptr, nullptr, 32, w2H, w2L, b_off2, nullptr, o2P, nullptr);
  // warp -> NCHW f32 [split-3]
  conv3x3_mfma_k<64, 288, 32, 0, 0, 3><<<dim3(4608), blk, 0, stream>>>(
      keyP, nullptr, o2P, nullptr, 32, wdH, wdL, b_dcn, warp, nullptr, nullptr);
  // corr + top-3
  corr_topk_k<<<dim3(128, 2), blk, 0, stream>>>(warp, x, idxb);
  // kwP borders (keyP region now dead), then selconv fills interior
  zero_border32_k<<<dim3(5, 2), blk, 0, stream>>>(kwP, PREC, kwP, PREC, kwP, PREC, kwP, PREC);
  selconv_k<<<dim3(8, 32, 2), blk, 0, stream>>>(warp, idxb, w_sel, b_sel, kwP);

  // tail borders (warp region dead after selconv) + phase-2 tables
  zero_border32_k<<<dim3(5, 8), blk, 0, stream>>>(
      t2P, 4 * PREC, t2P + PREC * 32, 4 * PREC, t2P + 2 * PREC * 32, 4 * PREC, t2P + 3 * PREC * 32, 4 * PREC);
  zero_border32_k<<<dim3(5, 2), blk, 0, stream>>>(t4P, PREC, t4P, PREC, t4P, PREC, t4P, PREC);
  prep3_w_k<<<dim3(648), blk, 0, stream>>>(
      w_t1, t1H_w, t1L_w, 32, 32, 36,
      w_t3, t3H_w, t3L_w, 128, 128, 576,
      w_t5, t5H_w, t5L_w, 32, 32);

  // t1: conv3x3 (gelu) -> NHWC f16 y1            [single-f16, gll from kwP]
  conv3x3_mfma_k<32, 32, 32, 2, 3, 1><<<dim3(512), blk, 0, stream>>>(
      kwP, nullptr, nullptr, nullptr, 32, t1H_w, t1L_w, nullptr, nullptr, y1, nullptr);
  // t2: 1x1 (gelu) -> padded chunked t2P
  conv1x1_nhwc_k<32, 16, 2><<<dim3(64, 2, 8), blk, 0, stream>>>(y1, w_t2, t2P, 128);
  // t3: conv3x3 (gelu) -> NHWC f16 y3            [single-f16, OCB=64, gll from t2P]
  conv3x3_mfma_k<128, 128, 64, 2, 3, 1><<<dim3(1024), blk, 0, stream>>>(
      t2P, nullptr, nullptr, nullptr, 128, t3H_w, t3L_w, nullptr, nullptr, y3, nullptr);
  // t4: 1x1 (gelu) -> padded t4P
  conv1x1_nhwc_k<128, 16, 2><<<dim3(64, 2, 2), blk, 0, stream>>>(y3, w_t4, t4P, 32);
  // t5: conv3x3 -> NCHW f32 final                [single-f16, gll from t4P]
  conv3x3_mfma_k<32, 32, 32, 0, 0, 1><<<dim3(512), blk, 0, stream>>>(
      t4P, nullptr, nullptr, nullptr, 32, t5H_w, t5L_w, nullptr, out, nullptr, nullptr);
}